// Round 1
// baseline (3635.749 us; speedup 1.0000x reference)
//
#include <hip/hip_runtime.h>
#include <math.h>

// Problem constants
#define B_  8
#define S_  384
#define H_  12
#define HD_ 64
#define E_  768
#define D_  768

// ---------------------------------------------------------------------------
// GEMM: C[m,n] = sum_k A[m,k] * W[n,k] + bias[n]      (A: MxK, W: NxK, K=N=768)
// If PERM_OUT: write C in (B,H,S,HD) head-major layout instead of (M,N).
// 64x64 block tile, 256 threads (16x16), 4x4 microtile, BK=16.
// LDS stored transposed [k][row] with pad 68 (row stride 272B: 16B-aligned,
// (4*col+row)%32 write pattern -> 2-way conflict = free on gfx950).
// ---------------------------------------------------------------------------
template <bool PERM_OUT>
__global__ __launch_bounds__(256) void gemm_at(
    const float* __restrict__ A, const float* __restrict__ W,
    const float* __restrict__ bias, float* __restrict__ C, int M)
{
    const int K = 768;
    __shared__ float As[16][68];
    __shared__ float Ws[16][68];

    const int tid = threadIdx.x;
    const int ty = tid >> 4, tx = tid & 15;
    const int m0 = blockIdx.y * 64, n0 = blockIdx.x * 64;

    float acc[4][4] = {};

    for (int k0 = 0; k0 < K; k0 += 16) {
#pragma unroll
        for (int r = 0; r < 4; ++r) {
            int idx = tid + 256 * r;          // 0..1023
            int row = idx >> 4, col = idx & 15;
            int gm = m0 + row;
            As[col][row] = (gm < M) ? A[(size_t)gm * K + k0 + col] : 0.f;
            Ws[col][row] = W[(size_t)(n0 + row) * K + k0 + col];
        }
        __syncthreads();
#pragma unroll
        for (int kk = 0; kk < 16; ++kk) {
            float a[4], w[4];
#pragma unroll
            for (int i = 0; i < 4; ++i) a[i] = As[kk][ty * 4 + i];
#pragma unroll
            for (int j = 0; j < 4; ++j) w[j] = Ws[kk][tx * 4 + j];
#pragma unroll
            for (int i = 0; i < 4; ++i)
#pragma unroll
                for (int j = 0; j < 4; ++j)
                    acc[i][j] = fmaf(a[i], w[j], acc[i][j]);
        }
        __syncthreads();
    }

#pragma unroll
    for (int i = 0; i < 4; ++i) {
        int m = m0 + ty * 4 + i;
        if (m >= M) continue;
#pragma unroll
        for (int j = 0; j < 4; ++j) {
            int n = n0 + tx * 4 + j;
            float val = acc[i][j] + bias[n];
            if (PERM_OUT) {
                int b = m / S_, s = m - b * S_;
                int h = n >> 6, hd = n & 63;
                C[(((size_t)(b * H_ + h) * S_ + s) << 6) + hd] = val;
            } else {
                C[(size_t)m * 768 + n] = val;
            }
        }
    }
}

// ---------------------------------------------------------------------------
// Fused attention. One block per (b,h,i); 384 threads, one per j.
// q,k,v in (B,H,S,HD); pk,pq indexed by dd = i-j+383 in (767,E) with head
// offset h*64. Writes vals in (B,S,E) layout so the output projection is a
// plain GEMM.
// ---------------------------------------------------------------------------
__global__ __launch_bounds__(384) void attn_kernel(
    const float* __restrict__ q, const float* __restrict__ k,
    const float* __restrict__ v, const float* __restrict__ pk,
    const float* __restrict__ pq, const int* __restrict__ seg,
    const float* __restrict__ sep, const int* __restrict__ mask,
    const float* __restrict__ same_bias, const float* __restrict__ cross_bias,
    const float* __restrict__ sep_scale, const float* __restrict__ sep_decay,
    float* __restrict__ vals)
{
    const int i = blockIdx.x, h = blockIdx.y, b = blockIdx.z;
    const int tid = threadIdx.x;   // 0..383 == j

    __shared__ float q_sh[HD_];
    __shared__ float w_sh[S_];
    __shared__ float red_sh[8];
    __shared__ float part_sh[6][HD_];

    const float* kbase = k + (size_t)(b * H_ + h) * S_ * HD_;
    const float* vbase = v + (size_t)(b * H_ + h) * S_ * HD_;

    if (tid < HD_) q_sh[tid] = q[((size_t)(b * H_ + h) * S_ + i) * HD_ + tid];
    __syncthreads();

    const int j = tid;
    const int dd = i - j + (S_ - 1);   // 0..766

    const float4* k4  = (const float4*)(kbase + (size_t)j * HD_);
    const float4* pk4 = (const float4*)(pk + (size_t)dd * E_ + h * HD_);
    const float4* pq4 = (const float4*)(pq + (size_t)dd * E_ + h * HD_);
    const float4* q4  = (const float4*)q_sh;

    float c = 0.f;
#pragma unroll
    for (int t = 0; t < 16; ++t) {
        float4 kv = k4[t], qv = q4[t], pkv = pk4[t], pqv = pq4[t];
        c += qv.x * kv.x + qv.y * kv.y + qv.z * kv.z + qv.w * kv.w;     // c2c
        c += qv.x * pkv.x + qv.y * pkv.y + qv.z * pkv.z + qv.w * pkv.w; // c2p
        c += pqv.x * kv.x + pqv.y * kv.y + pqv.z * kv.z + pqv.w * kv.w; // p2c
    }
    float logit = c * 0.07216878364870323f;   // 1/sqrt(64*3)

    // segment / separator bias
    int   si = seg[b * S_ + i], sj = seg[b * S_ + j];
    float ai = fabsf(sep[b * S_ + i]), aj = fabsf(sep[b * S_ + j]);
    float gap = fabsf(ai - aj);
    float sd  = sep_decay[h];
    float dec = fmaxf(sd, 0.f) + log1pf(expf(-fabsf(sd))) + 1e-4f;  // softplus + 1e-4
    if (si == sj) logit += same_bias[h];
    else          logit += cross_bias[h] + expf(-gap * dec) * sep_scale[h];
    if (mask[b * S_ + j] == 0) logit = -9.0e15f;

    // ---- softmax over j (384 threads = 6 waves) ----
    const int wave = tid >> 6;
    float m = logit;
#pragma unroll
    for (int o = 32; o > 0; o >>= 1) m = fmaxf(m, __shfl_down(m, o));
    if ((tid & 63) == 0) red_sh[wave] = m;
    __syncthreads();
    if (tid == 0) {
        float mm = red_sh[0];
#pragma unroll
        for (int w = 1; w < 6; ++w) mm = fmaxf(mm, red_sh[w]);
        red_sh[6] = mm;
    }
    __syncthreads();
    float gm = red_sh[6];
    float e  = expf(logit - gm);
    float s  = e;
#pragma unroll
    for (int o = 32; o > 0; o >>= 1) s += __shfl_down(s, o);
    if ((tid & 63) == 0) red_sh[wave] = s;
    __syncthreads();
    if (tid == 0) {
        float ss = 0.f;
#pragma unroll
        for (int w = 0; w < 6; ++w) ss += red_sh[w];
        red_sh[7] = ss;
    }
    __syncthreads();
    float inv = 1.f / red_sh[7];
    w_sh[j] = e * inv;
    __syncthreads();

    // ---- PV: out[d] = sum_j w[j] * v[j,d] ----
    {
        const int d = tid & 63, g = tid >> 6;   // 6 groups of 64
        float acc = 0.f;
        for (int jj = g; jj < S_; jj += 6)
            acc += w_sh[jj] * vbase[(size_t)jj * HD_ + d];
        part_sh[g][d] = acc;
    }
    __syncthreads();
    if (tid < HD_) {
        float ssum = 0.f;
#pragma unroll
        for (int g = 0; g < 6; ++g) ssum += part_sh[g][tid];
        vals[((size_t)(b * S_ + i)) * E_ + h * HD_ + tid] = ssum;
    }
}

// ---------------------------------------------------------------------------
// Launcher. Workspace layout (floats), all offsets 16B-aligned:
//   q, k, v, vals : 4 x B*H*S*HD = 4 x 2359296
//   pk, pq        : 2 x 767*768  = 2 x  589056
// total 10,615,296 floats = 42.5 MB (must fit ws_size).
// ---------------------------------------------------------------------------
extern "C" void kernel_launch(void* const* d_in, const int* in_sizes, int n_in,
                              void* d_out, int out_size, void* d_ws, size_t ws_size,
                              hipStream_t stream)
{
    const float* x         = (const float*)d_in[0];
    const int*   mask      = (const int*)d_in[1];
    const int*   seg       = (const int*)d_in[2];
    const float* sep       = (const float*)d_in[3];
    const float* Wq        = (const float*)d_in[4];
    const float* bq        = (const float*)d_in[5];
    const float* Wk        = (const float*)d_in[6];
    const float* bk        = (const float*)d_in[7];
    const float* Wv        = (const float*)d_in[8];
    const float* bv        = (const float*)d_in[9];
    const float* rel_emb   = (const float*)d_in[10];
    const float* Wpk       = (const float*)d_in[11];
    const float* bpk       = (const float*)d_in[12];
    const float* Wpq       = (const float*)d_in[13];
    const float* bpq       = (const float*)d_in[14];
    const float* same_bias = (const float*)d_in[15];
    const float* cross_bias= (const float*)d_in[16];
    const float* sep_scale = (const float*)d_in[17];
    const float* sep_decay = (const float*)d_in[18];
    const float* Wo        = (const float*)d_in[19];
    const float* bo        = (const float*)d_in[20];

    float* ws = (float*)d_ws;
    const size_t QKVN = (size_t)B_ * H_ * S_ * HD_;   // 2359296
    const size_t PN   = (size_t)767 * E_;             //  589056
    float* q    = ws;
    float* kbuf = q + QKVN;
    float* vbuf = kbuf + QKVN;
    float* vals = vbuf + QKVN;
    float* pk   = vals + QKVN;
    float* pq   = pk + PN;

    const int M  = B_ * S_;    // 3072
    dim3 blk(256);
    dim3 grid_qkv(E_ / 64, M / 64);          // 12 x 48
    dim3 grid_pos(E_ / 64, (767 + 63) / 64); // 12 x 12

    // QKV projections -> head-major (B,H,S,HD)
    gemm_at<true><<<grid_qkv, blk, 0, stream>>>(x, Wq, bq, q,    M);
    gemm_at<true><<<grid_qkv, blk, 0, stream>>>(x, Wk, bk, kbuf, M);
    gemm_at<true><<<grid_qkv, blk, 0, stream>>>(x, Wv, bv, vbuf, M);

    // Positional projections over the 767 used rel_emb rows [128, 894]
    gemm_at<false><<<grid_pos, blk, 0, stream>>>(rel_emb + (size_t)128 * D_, Wpk, bpk, pk, 767);
    gemm_at<false><<<grid_pos, blk, 0, stream>>>(rel_emb + (size_t)128 * D_, Wpq, bpq, pq, 767);

    // Fused disentangled attention + softmax + PV
    dim3 agrid(S_, H_, B_);
    attn_kernel<<<agrid, dim3(S_), 0, stream>>>(q, kbuf, vbuf, pk, pq, seg, sep, mask,
                                                same_bias, cross_bias, sep_scale, sep_decay,
                                                vals);

    // Output projection
    gemm_at<false><<<grid_qkv, blk, 0, stream>>>(vals, Wo, bo, (float*)d_out, M);
}

// Round 2
// 909.975 us; speedup vs baseline: 3.9954x; 3.9954x over previous
//
#include <hip/hip_runtime.h>
#include <math.h>

// Problem constants
#define B_  8
#define S_  384
#define H_  12
#define HD_ 64
#define E_  768
#define D_  768

// ---------------------------------------------------------------------------
// GEMM: C[m,n] = sum_k A[m,k] * W[n,k] + bias[n]      (A: MxK, W: NxK, K=N=768)
// If PERM_OUT: write C in (B,H,S,HD) head-major layout instead of (M,N).
// ---------------------------------------------------------------------------
template <bool PERM_OUT>
__global__ __launch_bounds__(256) void gemm_at(
    const float* __restrict__ A, const float* __restrict__ W,
    const float* __restrict__ bias, float* __restrict__ C, int M)
{
    const int K = 768;
    __shared__ float As[16][68];
    __shared__ float Ws[16][68];

    const int tid = threadIdx.x;
    const int ty = tid >> 4, tx = tid & 15;
    const int m0 = blockIdx.y * 64, n0 = blockIdx.x * 64;

    float acc[4][4] = {};

    for (int k0 = 0; k0 < K; k0 += 16) {
#pragma unroll
        for (int r = 0; r < 4; ++r) {
            int idx = tid + 256 * r;          // 0..1023
            int row = idx >> 4, col = idx & 15;
            int gm = m0 + row;
            As[col][row] = (gm < M) ? A[(size_t)gm * K + k0 + col] : 0.f;
            Ws[col][row] = W[(size_t)(n0 + row) * K + k0 + col];
        }
        __syncthreads();
#pragma unroll
        for (int kk = 0; kk < 16; ++kk) {
            float a[4], w[4];
#pragma unroll
            for (int i = 0; i < 4; ++i) a[i] = As[kk][ty * 4 + i];
#pragma unroll
            for (int j = 0; j < 4; ++j) w[j] = Ws[kk][tx * 4 + j];
#pragma unroll
            for (int i = 0; i < 4; ++i)
#pragma unroll
                for (int j = 0; j < 4; ++j)
                    acc[i][j] = fmaf(a[i], w[j], acc[i][j]);
        }
        __syncthreads();
    }

#pragma unroll
    for (int i = 0; i < 4; ++i) {
        int m = m0 + ty * 4 + i;
        if (m >= M) continue;
#pragma unroll
        for (int j = 0; j < 4; ++j) {
            int n = n0 + tx * 4 + j;
            float val = acc[i][j] + bias[n];
            if (PERM_OUT) {
                int b = m / S_, s = m - b * S_;
                int h = n >> 6, hd = n & 63;
                C[(((size_t)(b * H_ + h) * S_ + s) << 6) + hd] = val;
            } else {
                C[(size_t)m * 768 + n] = val;
            }
        }
    }
}

// ---------------------------------------------------------------------------
// Tiled flash-style disentangled attention.
// Block = (i-tile of 64, h, b); 256 threads as 16x16; thread owns a 4x4
// microtile of the 64x64 S tile (rows ii=4*ty+p, cols jj=4*tx+r).
// All operands staged in LDS with XOR swizzle (col4 ^= (row>>2)&7) to keep
// row-stride-4 b128 reads at <=2-way bank conflicts.
// pk/pq rows needed per (i-tile, j-tile): dd = i-j+383 spans 127 rows.
// Online softmax (flash); P round-trips LDS for the PV accumulation.
// ---------------------------------------------------------------------------
#define TI 64
#define TJ 64
#define NJT (S_ / TJ)   // 6

__device__ __forceinline__ int swz(int row, int c4) {
    return ((c4 ^ ((row >> 2) & 7)) << 2);
}

__global__ __launch_bounds__(256) void attn_tiled(
    const float* __restrict__ q, const float* __restrict__ k,
    const float* __restrict__ v, const float* __restrict__ pk,
    const float* __restrict__ pq, const int* __restrict__ seg,
    const float* __restrict__ sep, const int* __restrict__ mask,
    const float* __restrict__ same_bias, const float* __restrict__ cross_bias,
    const float* __restrict__ sep_scale, const float* __restrict__ sep_decay,
    float* __restrict__ vals)
{
    __shared__ float qs[TI * 64];
    __shared__ float ks[TJ * 64];
    __shared__ float vs[TJ * 64];
    __shared__ float Ps[TI * 64];
    __shared__ float pks[127 * 64];
    __shared__ float pqs[127 * 64];
    __shared__ float ai_s[TI];
    __shared__ int   si_s[TI];
    __shared__ float aj_s[TJ];
    __shared__ int   sj_s[TJ];
    __shared__ int   mj_s[TJ];

    const int tid = threadIdx.x;
    const int ty = tid >> 4, tx = tid & 15;
    const int it = blockIdx.x, h = blockIdx.y, b = blockIdx.z;
    const int i0 = it * TI;

    const float* qg = q + ((size_t)(b * H_ + h) * S_ + i0) * HD_;
    const float* kg = k + (size_t)(b * H_ + h) * S_ * HD_;
    const float* vg = v + (size_t)(b * H_ + h) * S_ * HD_;

    // per-head scalars
    const float sb  = same_bias[h];
    const float cb  = cross_bias[h];
    const float ssc = sep_scale[h];
    const float sd  = sep_decay[h];
    const float dec = fmaxf(sd, 0.f) + log1pf(__expf(-fabsf(sd))) + 1e-4f;
    const float isc = 0.07216878364870323f;   // 1/sqrt(64*3)

    // stage q tile + i-side arrays (consumed after first in-loop barrier)
#pragma unroll
    for (int r = 0; r < 4; ++r) {
        int idx = tid + 256 * r;              // 0..1023
        int row = idx >> 4, c4 = idx & 15;
        *(float4*)&qs[row * 64 + swz(row, c4)] =
            *(const float4*)(qg + row * HD_ + c4 * 4);
    }
    if (tid < TI) {
        ai_s[tid] = fabsf(sep[b * S_ + i0 + tid]);
        si_s[tid] = seg[b * S_ + i0 + tid];
    }

    float  m_[4], l_[4];
    float4 o_[4];
#pragma unroll
    for (int p = 0; p < 4; ++p) {
        m_[p] = -INFINITY; l_[p] = 0.f;
        o_[p] = make_float4(0.f, 0.f, 0.f, 0.f);
    }

    for (int jt = 0; jt < NJT; ++jt) {
        const int j0 = jt * TJ;
        __syncthreads();   // previous PV / q-stage visibility before overwrite

        // ---- stage k,v tiles ----
#pragma unroll
        for (int r = 0; r < 4; ++r) {
            int idx = tid + 256 * r;
            int row = idx >> 4, c4 = idx & 15;
            int sw = swz(row, c4);
            *(float4*)&ks[row * 64 + sw] = *(const float4*)(kg + (size_t)(j0 + row) * HD_ + c4 * 4);
            *(float4*)&vs[row * 64 + sw] = *(const float4*)(vg + (size_t)(j0 + row) * HD_ + c4 * 4);
        }
        // ---- stage pk/pq rows dd in [dbase, dbase+126] ----
        const int dbase = i0 - j0 + 320;      // 0..640
        const float* pkg = pk + (size_t)dbase * E_ + h * HD_;
        const float* pqg = pq + (size_t)dbase * E_ + h * HD_;
#pragma unroll
        for (int r = 0; r < 8; ++r) {
            int idx = tid + 256 * r;          // 0..2047, need 0..2031
            if (idx < 127 * 16) {
                int row = idx >> 4, c4 = idx & 15;
                int sw = swz(row, c4);
                *(float4*)&pks[row * 64 + sw] = *(const float4*)(pkg + (size_t)row * E_ + c4 * 4);
                *(float4*)&pqs[row * 64 + sw] = *(const float4*)(pqg + (size_t)row * E_ + c4 * 4);
            }
        }
        if (tid < TJ) {
            aj_s[tid] = fabsf(sep[b * S_ + j0 + tid]);
            sj_s[tid] = seg[b * S_ + j0 + tid];
            mj_s[tid] = mask[b * S_ + j0 + tid];
        }
        __syncthreads();

        // ---- scores: c2c + c2p + p2c over d=64 ----
        float s_[4][4];
#pragma unroll
        for (int p = 0; p < 4; ++p)
#pragma unroll
            for (int r = 0; r < 4; ++r) s_[p][r] = 0.f;

        const int rowbase = 4 * (ty - tx) + 60;        // 0..120, multiple of 4
        const int qsw = ty & 7, ksw = tx & 7;
        const int pb0 = (ty - tx + 15) & 7;            // (rowbase>>2)&7, u<4
        const int pb1 = (ty - tx + 16) & 7;            // u>=4

        for (int d4 = 0; d4 < 16; ++d4) {
            float4 qv[4], kv[4], pkv[7], pqv[7];
#pragma unroll
            for (int p = 0; p < 4; ++p)
                qv[p] = *(const float4*)&qs[(4 * ty + p) * 64 + ((d4 ^ qsw) << 2)];
#pragma unroll
            for (int r = 0; r < 4; ++r)
                kv[r] = *(const float4*)&ks[(4 * tx + r) * 64 + ((d4 ^ ksw) << 2)];
#pragma unroll
            for (int u = 0; u < 7; ++u) {
                int sw = ((d4 ^ (u < 4 ? pb0 : pb1)) << 2);
                pkv[u] = *(const float4*)&pks[(rowbase + u) * 64 + sw];
                pqv[u] = *(const float4*)&pqs[(rowbase + u) * 64 + sw];
            }
#pragma unroll
            for (int p = 0; p < 4; ++p)
#pragma unroll
                for (int r = 0; r < 4; ++r) {
                    const int u = p - r + 3;           // 0..6
                    float acc = s_[p][r];
                    float tx0 = kv[r].x + pkv[u].x;
                    float tx1 = kv[r].y + pkv[u].y;
                    float tx2 = kv[r].z + pkv[u].z;
                    float tx3 = kv[r].w + pkv[u].w;
                    acc = fmaf(qv[p].x, tx0, acc);
                    acc = fmaf(qv[p].y, tx1, acc);
                    acc = fmaf(qv[p].z, tx2, acc);
                    acc = fmaf(qv[p].w, tx3, acc);
                    acc = fmaf(pqv[u].x, kv[r].x, acc);
                    acc = fmaf(pqv[u].y, kv[r].y, acc);
                    acc = fmaf(pqv[u].z, kv[r].z, acc);
                    acc = fmaf(pqv[u].w, kv[r].w, acc);
                    s_[p][r] = acc;
                }
        }

        // ---- bias + mask + online softmax ----
#pragma unroll
        for (int p = 0; p < 4; ++p) {
            const int il = 4 * ty + p;
            const float aii = ai_s[il];
            const int   sii = si_s[il];
#pragma unroll
            for (int r = 0; r < 4; ++r) {
                const int jl = 4 * tx + r;
                float lg = s_[p][r] * isc;
                float gap = fabsf(aii - aj_s[jl]);
                float bias = (sii == sj_s[jl]) ? sb
                           : cb + __expf(-gap * dec) * ssc;
                lg += bias;
                if (mj_s[jl] == 0) lg = -9.0e15f;
                s_[p][r] = lg;
            }
        }

#pragma unroll
        for (int p = 0; p < 4; ++p) {
            float tm = fmaxf(fmaxf(s_[p][0], s_[p][1]), fmaxf(s_[p][2], s_[p][3]));
#pragma unroll
            for (int off = 1; off < 16; off <<= 1)
                tm = fmaxf(tm, __shfl_xor(tm, off));
            const float nm = fmaxf(m_[p], tm);
            const float alpha = __expf(m_[p] - nm);
            float rowsum = 0.f;
#pragma unroll
            for (int r = 0; r < 4; ++r) {
                float pv = __expf(s_[p][r] - nm);
                s_[p][r] = pv;
                rowsum += pv;
            }
#pragma unroll
            for (int off = 1; off < 16; off <<= 1)
                rowsum += __shfl_xor(rowsum, off);
            l_[p] = l_[p] * alpha + rowsum;
            m_[p] = nm;
            o_[p].x *= alpha; o_[p].y *= alpha; o_[p].z *= alpha; o_[p].w *= alpha;
            // write P row 4*ty+p, cols 4*tx..4*tx+3 (c4 = tx)
            *(float4*)&Ps[(4 * ty + p) * 64 + swz(4 * ty + p, tx)] =
                make_float4(s_[p][0], s_[p][1], s_[p][2], s_[p][3]);
        }
        __syncthreads();

        // ---- PV: O[ii][4*tx..] += P[ii][jj] * V[jj][4*tx..] ----
        for (int jj4 = 0; jj4 < 16; ++jj4) {
            float4 pvv[4], vv[4];
#pragma unroll
            for (int p = 0; p < 4; ++p)
                pvv[p] = *(const float4*)&Ps[(4 * ty + p) * 64 + ((jj4 ^ (ty & 7)) << 2)];
#pragma unroll
            for (int w = 0; w < 4; ++w)
                vv[w] = *(const float4*)&vs[(4 * jj4 + w) * 64 + ((tx ^ (jj4 & 7)) << 2)];
#pragma unroll
            for (int p = 0; p < 4; ++p) {
                o_[p].x = fmaf(pvv[p].x, vv[0].x, o_[p].x);
                o_[p].y = fmaf(pvv[p].x, vv[0].y, o_[p].y);
                o_[p].z = fmaf(pvv[p].x, vv[0].z, o_[p].z);
                o_[p].w = fmaf(pvv[p].x, vv[0].w, o_[p].w);
                o_[p].x = fmaf(pvv[p].y, vv[1].x, o_[p].x);
                o_[p].y = fmaf(pvv[p].y, vv[1].y, o_[p].y);
                o_[p].z = fmaf(pvv[p].y, vv[1].z, o_[p].z);
                o_[p].w = fmaf(pvv[p].y, vv[1].w, o_[p].w);
                o_[p].x = fmaf(pvv[p].z, vv[2].x, o_[p].x);
                o_[p].y = fmaf(pvv[p].z, vv[2].y, o_[p].y);
                o_[p].z = fmaf(pvv[p].z, vv[2].z, o_[p].z);
                o_[p].w = fmaf(pvv[p].z, vv[2].w, o_[p].w);
                o_[p].x = fmaf(pvv[p].w, vv[3].x, o_[p].x);
                o_[p].y = fmaf(pvv[p].w, vv[3].y, o_[p].y);
                o_[p].z = fmaf(pvv[p].w, vv[3].z, o_[p].z);
                o_[p].w = fmaf(pvv[p].w, vv[3].w, o_[p].w);
            }
        }
    }

    // ---- epilogue: normalize, write vals in (B,S,E) ----
#pragma unroll
    for (int p = 0; p < 4; ++p) {
        const float inv = 1.f / l_[p];
        float4 ov = make_float4(o_[p].x * inv, o_[p].y * inv, o_[p].z * inv, o_[p].w * inv);
        const int i = i0 + 4 * ty + p;
        *(float4*)&vals[(size_t)(b * S_ + i) * E_ + h * HD_ + 4 * tx] = ov;
    }
}

// ---------------------------------------------------------------------------
// Launcher. Workspace (floats): q,k,v,vals 4 x 2359296; pk,pq 2 x 589056.
// ---------------------------------------------------------------------------
extern "C" void kernel_launch(void* const* d_in, const int* in_sizes, int n_in,
                              void* d_out, int out_size, void* d_ws, size_t ws_size,
                              hipStream_t stream)
{
    const float* x         = (const float*)d_in[0];
    const int*   mask      = (const int*)d_in[1];
    const int*   seg       = (const int*)d_in[2];
    const float* sep       = (const float*)d_in[3];
    const float* Wq        = (const float*)d_in[4];
    const float* bq        = (const float*)d_in[5];
    const float* Wk        = (const float*)d_in[6];
    const float* bk        = (const float*)d_in[7];
    const float* Wv        = (const float*)d_in[8];
    const float* bv        = (const float*)d_in[9];
    const float* rel_emb   = (const float*)d_in[10];
    const float* Wpk       = (const float*)d_in[11];
    const float* bpk       = (const float*)d_in[12];
    const float* Wpq       = (const float*)d_in[13];
    const float* bpq       = (const float*)d_in[14];
    const float* same_bias = (const float*)d_in[15];
    const float* cross_bias= (const float*)d_in[16];
    const float* sep_scale = (const float*)d_in[17];
    const float* sep_decay = (const float*)d_in[18];
    const float* Wo        = (const float*)d_in[19];
    const float* bo        = (const float*)d_in[20];

    float* ws = (float*)d_ws;
    const size_t QKVN = (size_t)B_ * H_ * S_ * HD_;   // 2359296
    const size_t PN   = (size_t)767 * E_;             //  589056
    float* q    = ws;
    float* kbuf = q + QKVN;
    float* vbuf = kbuf + QKVN;
    float* vals = vbuf + QKVN;
    float* pk   = vals + QKVN;
    float* pq   = pk + PN;

    const int M = B_ * S_;    // 3072
    dim3 blk(256);
    dim3 grid_qkv(E_ / 64, M / 64);          // 12 x 48
    dim3 grid_pos(E_ / 64, (767 + 63) / 64); // 12 x 12

    gemm_at<true><<<grid_qkv, blk, 0, stream>>>(x, Wq, bq, q,    M);
    gemm_at<true><<<grid_qkv, blk, 0, stream>>>(x, Wk, bk, kbuf, M);
    gemm_at<true><<<grid_qkv, blk, 0, stream>>>(x, Wv, bv, vbuf, M);

    gemm_at<false><<<grid_pos, blk, 0, stream>>>(rel_emb + (size_t)128 * D_, Wpk, bpk, pk, 767);
    gemm_at<false><<<grid_pos, blk, 0, stream>>>(rel_emb + (size_t)128 * D_, Wpq, bpq, pq, 767);

    dim3 agrid(S_ / TI, H_, B_);             // 6 x 12 x 8
    attn_tiled<<<agrid, blk, 0, stream>>>(q, kbuf, vbuf, pk, pq, seg, sep, mask,
                                          same_bias, cross_bias, sep_scale, sep_decay,
                                          vals);

    gemm_at<false><<<grid_qkv, blk, 0, stream>>>(vals, Wo, bo, (float*)d_out, M);
}

// Round 3
// 464.280 us; speedup vs baseline: 7.8309x; 1.9600x over previous
//
#include <hip/hip_runtime.h>
#include <math.h>

// Problem constants
#define B_  8
#define S_  384
#define H_  12
#define HD_ 64
#define E_  768
#define D_  768

typedef float  floatx4 __attribute__((ext_vector_type(4)));
typedef __bf16 bf16x8  __attribute__((ext_vector_type(8)));
typedef unsigned int ux4 __attribute__((ext_vector_type(4)));

__device__ __forceinline__ unsigned short f2bf(float f) {
    union { float f; unsigned u; } x; x.f = f;
    unsigned r = x.u + 0x7fff + ((x.u >> 16) & 1);
    return (unsigned short)(r >> 16);
}

// ---------------------------------------------------------------------------
// Fused fp32 -> bf16 convert for all GEMM operands.
// grid = (576, 11); each block converts 1024 contiguous floats of one segment
// (segments are all 589824 elements).
//  seg 0-3 : x (+ seg*589824)          -> xb
//  seg 4-7 : Wq,Wk,Wv,Wo               -> wqb,wkb,wvb,wob
//  seg 8-9 : Wpk,Wpq                   -> wpkb,wpqb
//  seg 10  : rel_emb rows 128..894     -> relb (row 767 zeroed)
// ---------------------------------------------------------------------------
__global__ __launch_bounds__(256) void convert_all(
    const float* __restrict__ x,
    const float* __restrict__ Wq, const float* __restrict__ Wk,
    const float* __restrict__ Wv, const float* __restrict__ Wo,
    const float* __restrict__ Wpk, const float* __restrict__ Wpq,
    const float* __restrict__ rel128,
    unsigned short* __restrict__ xb,
    unsigned short* __restrict__ wqb, unsigned short* __restrict__ wkb,
    unsigned short* __restrict__ wvb, unsigned short* __restrict__ wob,
    unsigned short* __restrict__ wpkb, unsigned short* __restrict__ wpqb,
    unsigned short* __restrict__ relb)
{
    const int seg = blockIdx.y;
    const int e = (blockIdx.x * 256 + threadIdx.x) * 4;
    const float* src;
    unsigned short* dst;
    if (seg < 4)       { src = x + (size_t)seg * 589824; dst = xb + (size_t)seg * 589824; }
    else if (seg == 4) { src = Wq;  dst = wqb; }
    else if (seg == 5) { src = Wk;  dst = wkb; }
    else if (seg == 6) { src = Wv;  dst = wvb; }
    else if (seg == 7) { src = Wo;  dst = wob; }
    else if (seg == 8) { src = Wpk; dst = wpkb; }
    else if (seg == 9) { src = Wpq; dst = wpqb; }
    else               { src = rel128; dst = relb; }

    float4 v;
    if (seg == 10 && e >= 767 * 768) v = make_float4(0.f, 0.f, 0.f, 0.f);
    else                             v = *(const float4*)(src + e);
    ushort4 o;
    o.x = f2bf(v.x); o.y = f2bf(v.y); o.z = f2bf(v.z); o.w = f2bf(v.w);
    *(ushort4*)(dst + e) = o;
}

// ---------------------------------------------------------------------------
// bf16 MFMA GEMM: C[m,n] = A[m,:] . W[n,:] + bias[n]   (K = 768, N mult of 128)
// 128x128 block tile, BK=32, 256 threads = 4 waves (2x2), each wave 64x64 via
// 4x4 mfma_f32_16x16x32_bf16 fragments. global_load_lds width-16 staging.
// PERM: write fp32 C in (B,H,S,HD) head-major; else flat (M,768) fp32.
// ---------------------------------------------------------------------------
template <bool PERM>
__global__ __launch_bounds__(256) void gemm_mfma(
    const unsigned short* __restrict__ A, const unsigned short* __restrict__ W,
    const float* __restrict__ bias, float* __restrict__ C, int M)
{
    __shared__ unsigned short As[128 * 32];
    __shared__ unsigned short Ws[128 * 32];

    const int tid  = threadIdx.x;
    const int lane = tid & 63;
    const int wv   = tid >> 6;           // wave 0..3
    const int wy   = wv >> 1, wx = wv & 1;
    const int quad = lane >> 4, l16 = lane & 15;
    const int m0 = blockIdx.y * 128, n0 = blockIdx.x * 128;

    floatx4 acc[4][4];
#pragma unroll
    for (int i = 0; i < 4; ++i)
#pragma unroll
        for (int j = 0; j < 4; ++j) acc[i][j] = (floatx4){0.f, 0.f, 0.f, 0.f};

    const int koff = quad * 8;

    for (int k0 = 0; k0 < 768; k0 += 32) {
        __syncthreads();
#pragma unroll
        for (int r = 0; r < 2; ++r) {
            int idx = tid + 256 * r;                 // 0..511
            int row = idx >> 2, c8 = (idx & 3) * 8;
            const unsigned short* ga = A + (size_t)(m0 + row) * 768 + k0 + c8;
            const unsigned short* gw = W + (size_t)(n0 + row) * 768 + k0 + c8;
            __builtin_amdgcn_global_load_lds(
                (__attribute__((address_space(1))) void*)ga,
                (__attribute__((address_space(3))) void*)&As[idx * 8], 16, 0, 0);
            __builtin_amdgcn_global_load_lds(
                (__attribute__((address_space(1))) void*)gw,
                (__attribute__((address_space(3))) void*)&Ws[idx * 8], 16, 0, 0);
        }
        __syncthreads();

        bf16x8 a[4], b[4];
#pragma unroll
        for (int mi = 0; mi < 4; ++mi)
            a[mi] = __builtin_bit_cast(bf16x8,
                *(const ux4*)&As[(wy * 64 + mi * 16 + l16) * 32 + koff]);
#pragma unroll
        for (int ni = 0; ni < 4; ++ni)
            b[ni] = __builtin_bit_cast(bf16x8,
                *(const ux4*)&Ws[(wx * 64 + ni * 16 + l16) * 32 + koff]);
#pragma unroll
        for (int mi = 0; mi < 4; ++mi)
#pragma unroll
            for (int ni = 0; ni < 4; ++ni)
                acc[mi][ni] = __builtin_amdgcn_mfma_f32_16x16x32_bf16(
                    a[mi], b[ni], acc[mi][ni], 0, 0, 0);
    }

    // epilogue: C/D layout col=lane&15, row=quad*4+reg
#pragma unroll
    for (int ni = 0; ni < 4; ++ni) {
        const int n = n0 + wx * 64 + ni * 16 + l16;
        const float bn = bias[n];
#pragma unroll
        for (int mi = 0; mi < 4; ++mi) {
#pragma unroll
            for (int reg = 0; reg < 4; ++reg) {
                const int m = m0 + wy * 64 + mi * 16 + quad * 4 + reg;
                const float val = acc[mi][ni][reg] + bn;
                if (PERM) {
                    const int bb = m / S_, s = m - bb * S_;
                    const int h = n >> 6, hd = n & 63;
                    C[(((size_t)(bb * H_ + h) * S_ + s) << 6) + hd] = val;
                } else {
                    C[(size_t)m * 768 + n] = val;
                }
            }
        }
    }
}

// ---------------------------------------------------------------------------
// Tiled flash-style disentangled attention (unchanged from R1 except the
// epilogue writes bf16 vals). Block = (i-tile 64, h, b); 256 threads 16x16;
// XOR-swizzled LDS. Writes vals (B,S,E) bf16 for the MFMA output projection.
// ---------------------------------------------------------------------------
#define TI 64
#define TJ 64
#define NJT (S_ / TJ)   // 6

__device__ __forceinline__ int swz(int row, int c4) {
    return ((c4 ^ ((row >> 2) & 7)) << 2);
}

__global__ __launch_bounds__(256) void attn_tiled(
    const float* __restrict__ q, const float* __restrict__ k,
    const float* __restrict__ v, const float* __restrict__ pk,
    const float* __restrict__ pq, const int* __restrict__ seg,
    const float* __restrict__ sep, const int* __restrict__ mask,
    const float* __restrict__ same_bias, const float* __restrict__ cross_bias,
    const float* __restrict__ sep_scale, const float* __restrict__ sep_decay,
    unsigned short* __restrict__ vals)
{
    __shared__ float qs[TI * 64];
    __shared__ float ks[TJ * 64];
    __shared__ float vs[TJ * 64];
    __shared__ float Ps[TI * 64];
    __shared__ float pks[127 * 64];
    __shared__ float pqs[127 * 64];
    __shared__ float ai_s[TI];
    __shared__ int   si_s[TI];
    __shared__ float aj_s[TJ];
    __shared__ int   sj_s[TJ];
    __shared__ int   mj_s[TJ];

    const int tid = threadIdx.x;
    const int ty = tid >> 4, tx = tid & 15;
    const int it = blockIdx.x, h = blockIdx.y, b = blockIdx.z;
    const int i0 = it * TI;

    const float* qg = q + ((size_t)(b * H_ + h) * S_ + i0) * HD_;
    const float* kg = k + (size_t)(b * H_ + h) * S_ * HD_;
    const float* vg = v + (size_t)(b * H_ + h) * S_ * HD_;

    const float sb  = same_bias[h];
    const float cb  = cross_bias[h];
    const float ssc = sep_scale[h];
    const float sd  = sep_decay[h];
    const float dec = fmaxf(sd, 0.f) + log1pf(__expf(-fabsf(sd))) + 1e-4f;
    const float isc = 0.07216878364870323f;   // 1/sqrt(64*3)

#pragma unroll
    for (int r = 0; r < 4; ++r) {
        int idx = tid + 256 * r;
        int row = idx >> 4, c4 = idx & 15;
        *(float4*)&qs[row * 64 + swz(row, c4)] =
            *(const float4*)(qg + row * HD_ + c4 * 4);
    }
    if (tid < TI) {
        ai_s[tid] = fabsf(sep[b * S_ + i0 + tid]);
        si_s[tid] = seg[b * S_ + i0 + tid];
    }

    float  m_[4], l_[4];
    float4 o_[4];
#pragma unroll
    for (int p = 0; p < 4; ++p) {
        m_[p] = -INFINITY; l_[p] = 0.f;
        o_[p] = make_float4(0.f, 0.f, 0.f, 0.f);
    }

    for (int jt = 0; jt < NJT; ++jt) {
        const int j0 = jt * TJ;
        __syncthreads();

#pragma unroll
        for (int r = 0; r < 4; ++r) {
            int idx = tid + 256 * r;
            int row = idx >> 4, c4 = idx & 15;
            int sw = swz(row, c4);
            *(float4*)&ks[row * 64 + sw] = *(const float4*)(kg + (size_t)(j0 + row) * HD_ + c4 * 4);
            *(float4*)&vs[row * 64 + sw] = *(const float4*)(vg + (size_t)(j0 + row) * HD_ + c4 * 4);
        }
        const int dbase = i0 - j0 + 320;      // 0..640
        const float* pkg = pk + (size_t)dbase * E_ + h * HD_;
        const float* pqg = pq + (size_t)dbase * E_ + h * HD_;
#pragma unroll
        for (int r = 0; r < 8; ++r) {
            int idx = tid + 256 * r;
            if (idx < 127 * 16) {
                int row = idx >> 4, c4 = idx & 15;
                int sw = swz(row, c4);
                *(float4*)&pks[row * 64 + sw] = *(const float4*)(pkg + (size_t)row * E_ + c4 * 4);
                *(float4*)&pqs[row * 64 + sw] = *(const float4*)(pqg + (size_t)row * E_ + c4 * 4);
            }
        }
        if (tid < TJ) {
            aj_s[tid] = fabsf(sep[b * S_ + j0 + tid]);
            sj_s[tid] = seg[b * S_ + j0 + tid];
            mj_s[tid] = mask[b * S_ + j0 + tid];
        }
        __syncthreads();

        float s_[4][4];
#pragma unroll
        for (int p = 0; p < 4; ++p)
#pragma unroll
            for (int r = 0; r < 4; ++r) s_[p][r] = 0.f;

        const int rowbase = 4 * (ty - tx) + 60;
        const int qsw = ty & 7, ksw = tx & 7;
        const int pb0 = (ty - tx + 15) & 7;
        const int pb1 = (ty - tx + 16) & 7;

        for (int d4 = 0; d4 < 16; ++d4) {
            float4 qv[4], kv[4], pkv[7], pqv[7];
#pragma unroll
            for (int p = 0; p < 4; ++p)
                qv[p] = *(const float4*)&qs[(4 * ty + p) * 64 + ((d4 ^ qsw) << 2)];
#pragma unroll
            for (int r = 0; r < 4; ++r)
                kv[r] = *(const float4*)&ks[(4 * tx + r) * 64 + ((d4 ^ ksw) << 2)];
#pragma unroll
            for (int u = 0; u < 7; ++u) {
                int sw = ((d4 ^ (u < 4 ? pb0 : pb1)) << 2);
                pkv[u] = *(const float4*)&pks[(rowbase + u) * 64 + sw];
                pqv[u] = *(const float4*)&pqs[(rowbase + u) * 64 + sw];
            }
#pragma unroll
            for (int p = 0; p < 4; ++p)
#pragma unroll
                for (int r = 0; r < 4; ++r) {
                    const int u = p - r + 3;
                    float acc = s_[p][r];
                    float t0 = kv[r].x + pkv[u].x;
                    float t1 = kv[r].y + pkv[u].y;
                    float t2 = kv[r].z + pkv[u].z;
                    float t3 = kv[r].w + pkv[u].w;
                    acc = fmaf(qv[p].x, t0, acc);
                    acc = fmaf(qv[p].y, t1, acc);
                    acc = fmaf(qv[p].z, t2, acc);
                    acc = fmaf(qv[p].w, t3, acc);
                    acc = fmaf(pqv[u].x, kv[r].x, acc);
                    acc = fmaf(pqv[u].y, kv[r].y, acc);
                    acc = fmaf(pqv[u].z, kv[r].z, acc);
                    acc = fmaf(pqv[u].w, kv[r].w, acc);
                    s_[p][r] = acc;
                }
        }

#pragma unroll
        for (int p = 0; p < 4; ++p) {
            const int il = 4 * ty + p;
            const float aii = ai_s[il];
            const int   sii = si_s[il];
#pragma unroll
            for (int r = 0; r < 4; ++r) {
                const int jl = 4 * tx + r;
                float lg = s_[p][r] * isc;
                float gap = fabsf(aii - aj_s[jl]);
                float bias = (sii == sj_s[jl]) ? sb
                           : cb + __expf(-gap * dec) * ssc;
                lg += bias;
                if (mj_s[jl] == 0) lg = -9.0e15f;
                s_[p][r] = lg;
            }
        }

#pragma unroll
        for (int p = 0; p < 4; ++p) {
            float tm = fmaxf(fmaxf(s_[p][0], s_[p][1]), fmaxf(s_[p][2], s_[p][3]));
#pragma unroll
            for (int off = 1; off < 16; off <<= 1)
                tm = fmaxf(tm, __shfl_xor(tm, off));
            const float nm = fmaxf(m_[p], tm);
            const float alpha = __expf(m_[p] - nm);
            float rowsum = 0.f;
#pragma unroll
            for (int r = 0; r < 4; ++r) {
                float pv = __expf(s_[p][r] - nm);
                s_[p][r] = pv;
                rowsum += pv;
            }
#pragma unroll
            for (int off = 1; off < 16; off <<= 1)
                rowsum += __shfl_xor(rowsum, off);
            l_[p] = l_[p] * alpha + rowsum;
            m_[p] = nm;
            o_[p].x *= alpha; o_[p].y *= alpha; o_[p].z *= alpha; o_[p].w *= alpha;
            *(float4*)&Ps[(4 * ty + p) * 64 + swz(4 * ty + p, tx)] =
                make_float4(s_[p][0], s_[p][1], s_[p][2], s_[p][3]);
        }
        __syncthreads();

        for (int jj4 = 0; jj4 < 16; ++jj4) {
            float4 pvv[4], vv[4];
#pragma unroll
            for (int p = 0; p < 4; ++p)
                pvv[p] = *(const float4*)&Ps[(4 * ty + p) * 64 + ((jj4 ^ (ty & 7)) << 2)];
#pragma unroll
            for (int w = 0; w < 4; ++w)
                vv[w] = *(const float4*)&vs[(4 * jj4 + w) * 64 + ((tx ^ (jj4 & 7)) << 2)];
#pragma unroll
            for (int p = 0; p < 4; ++p) {
                o_[p].x = fmaf(pvv[p].x, vv[0].x, o_[p].x);
                o_[p].y = fmaf(pvv[p].x, vv[0].y, o_[p].y);
                o_[p].z = fmaf(pvv[p].x, vv[0].z, o_[p].z);
                o_[p].w = fmaf(pvv[p].x, vv[0].w, o_[p].w);
                o_[p].x = fmaf(pvv[p].y, vv[1].x, o_[p].x);
                o_[p].y = fmaf(pvv[p].y, vv[1].y, o_[p].y);
                o_[p].z = fmaf(pvv[p].y, vv[1].z, o_[p].z);
                o_[p].w = fmaf(pvv[p].y, vv[1].w, o_[p].w);
                o_[p].x = fmaf(pvv[p].z, vv[2].x, o_[p].x);
                o_[p].y = fmaf(pvv[p].z, vv[2].y, o_[p].y);
                o_[p].z = fmaf(pvv[p].z, vv[2].z, o_[p].z);
                o_[p].w = fmaf(pvv[p].z, vv[2].w, o_[p].w);
                o_[p].x = fmaf(pvv[p].w, vv[3].x, o_[p].x);
                o_[p].y = fmaf(pvv[p].w, vv[3].y, o_[p].y);
                o_[p].z = fmaf(pvv[p].w, vv[3].z, o_[p].z);
                o_[p].w = fmaf(pvv[p].w, vv[3].w, o_[p].w);
            }
        }
    }

    // epilogue: normalize, write bf16 vals in (B,S,E)
#pragma unroll
    for (int p = 0; p < 4; ++p) {
        const float inv = 1.f / l_[p];
        const int i = i0 + 4 * ty + p;
        ushort4 ov;
        ov.x = f2bf(o_[p].x * inv);
        ov.y = f2bf(o_[p].y * inv);
        ov.z = f2bf(o_[p].z * inv);
        ov.w = f2bf(o_[p].w * inv);
        *(ushort4*)&vals[(size_t)(b * S_ + i) * E_ + h * HD_ + 4 * tx] = ov;
    }
}

// ---------------------------------------------------------------------------
// Launcher. Workspace: fp32 q,k,v (3x2359296) + pk,pq (2x589824) then bf16
// xb (2359296) + wqb,wkb,wvb,wob,relb,wpkb,wpqb (7x589824). vals_bf16 aliases
// xb (x is dead after the V projection). Total ~44 MiB.
// ---------------------------------------------------------------------------
extern "C" void kernel_launch(void* const* d_in, const int* in_sizes, int n_in,
                              void* d_out, int out_size, void* d_ws, size_t ws_size,
                              hipStream_t stream)
{
    const float* x         = (const float*)d_in[0];
    const int*   mask      = (const int*)d_in[1];
    const int*   seg       = (const int*)d_in[2];
    const float* sep       = (const float*)d_in[3];
    const float* Wq        = (const float*)d_in[4];
    const float* bq        = (const float*)d_in[5];
    const float* Wk        = (const float*)d_in[6];
    const float* bk        = (const float*)d_in[7];
    const float* Wv        = (const float*)d_in[8];
    const float* bv        = (const float*)d_in[9];
    const float* rel_emb   = (const float*)d_in[10];
    const float* Wpk       = (const float*)d_in[11];
    const float* bpk       = (const float*)d_in[12];
    const float* Wpq       = (const float*)d_in[13];
    const float* bpq       = (const float*)d_in[14];
    const float* same_bias = (const float*)d_in[15];
    const float* cross_bias= (const float*)d_in[16];
    const float* sep_scale = (const float*)d_in[17];
    const float* sep_decay = (const float*)d_in[18];
    const float* Wo        = (const float*)d_in[19];
    const float* bo        = (const float*)d_in[20];

    const size_t QKVN = (size_t)B_ * H_ * S_ * HD_;   // 2359296
    const size_t WN   = (size_t)768 * 768;            //  589824

    float* q  = (float*)d_ws;
    float* kf = q  + QKVN;
    float* vf = kf + QKVN;
    float* pk = vf + QKVN;
    float* pq = pk + WN;
    unsigned short* xb   = (unsigned short*)(pq + WN);
    unsigned short* wqb  = xb   + QKVN;
    unsigned short* wkb  = wqb  + WN;
    unsigned short* wvb  = wkb  + WN;
    unsigned short* wob  = wvb  + WN;
    unsigned short* relb = wob  + WN;
    unsigned short* wpkb = relb + WN;
    unsigned short* wpqb = wpkb + WN;
    unsigned short* valsb = xb;   // alias: x dead after V projection

    // 1) convert everything to bf16
    convert_all<<<dim3(576, 11), 256, 0, stream>>>(
        x, Wq, Wk, Wv, Wo, Wpk, Wpq, rel_emb + (size_t)128 * D_,
        xb, wqb, wkb, wvb, wob, wpkb, wpqb, relb);

    // 2) projections (MFMA)
    dim3 gq(E_ / 128, (B_ * S_) / 128);   // 6 x 24
    dim3 gp(E_ / 128, 768 / 128);         // 6 x 6
    gemm_mfma<true ><<<gq, 256, 0, stream>>>(xb,   wqb,  bq,  q,  B_ * S_);
    gemm_mfma<true ><<<gq, 256, 0, stream>>>(xb,   wkb,  bk,  kf, B_ * S_);
    gemm_mfma<true ><<<gq, 256, 0, stream>>>(xb,   wvb,  bv,  vf, B_ * S_);
    gemm_mfma<false><<<gp, 256, 0, stream>>>(relb, wpkb, bpk, pk, 768);
    gemm_mfma<false><<<gp, 256, 0, stream>>>(relb, wpqb, bpq, pq, 768);

    // 3) fused attention (writes bf16 vals over xb)
    dim3 agrid(S_ / TI, H_, B_);          // 6 x 12 x 8
    attn_tiled<<<agrid, 256, 0, stream>>>(q, kf, vf, pk, pq, seg, sep, mask,
                                          same_bias, cross_bias, sep_scale, sep_decay,
                                          valsb);

    // 4) output projection (MFMA)
    gemm_mfma<false><<<gq, 256, 0, stream>>>(valsb, wob, bo, (float*)d_out, B_ * S_);
}

// Round 4
// 421.031 us; speedup vs baseline: 8.6353x; 1.1027x over previous
//
#include <hip/hip_runtime.h>
#include <math.h>

// Problem constants
#define B_  8
#define S_  384
#define H_  12
#define HD_ 64
#define E_  768
#define D_  768

typedef float  floatx4 __attribute__((ext_vector_type(4)));
typedef __bf16 bf16x8  __attribute__((ext_vector_type(8)));
typedef unsigned int ux4 __attribute__((ext_vector_type(4)));

__device__ __forceinline__ unsigned short f2bf(float f) {
    union { float f; unsigned u; } x; x.f = f;
    unsigned r = x.u + 0x7fff + ((x.u >> 16) & 1);
    return (unsigned short)(r >> 16);
}

// ---------------------------------------------------------------------------
// Fused fp32 -> bf16 convert. grid=(576,11); 1024 floats per block-segment.
//  seg 0-3: x -> xb   seg 4-7: Wq,Wk,Wv,Wo   seg 8-9: Wpk,Wpq
//  seg 10 : rel_emb rows 128..894 -> relb (row 767 zeroed)
// ---------------------------------------------------------------------------
__global__ __launch_bounds__(256) void convert_all(
    const float* __restrict__ x,
    const float* __restrict__ Wq, const float* __restrict__ Wk,
    const float* __restrict__ Wv, const float* __restrict__ Wo,
    const float* __restrict__ Wpk, const float* __restrict__ Wpq,
    const float* __restrict__ rel128,
    unsigned short* __restrict__ xb,
    unsigned short* __restrict__ wqb, unsigned short* __restrict__ wkb,
    unsigned short* __restrict__ wvb, unsigned short* __restrict__ wob,
    unsigned short* __restrict__ wpkb, unsigned short* __restrict__ wpqb,
    unsigned short* __restrict__ relb)
{
    const int seg = blockIdx.y;
    const int e = (blockIdx.x * 256 + threadIdx.x) * 4;
    const float* src;
    unsigned short* dst;
    if (seg < 4)       { src = x + (size_t)seg * 589824; dst = xb + (size_t)seg * 589824; }
    else if (seg == 4) { src = Wq;  dst = wqb; }
    else if (seg == 5) { src = Wk;  dst = wkb; }
    else if (seg == 6) { src = Wv;  dst = wvb; }
    else if (seg == 7) { src = Wo;  dst = wob; }
    else if (seg == 8) { src = Wpk; dst = wpkb; }
    else if (seg == 9) { src = Wpq; dst = wpqb; }
    else               { src = rel128; dst = relb; }

    float4 v;
    if (seg == 10 && e >= 767 * 768) v = make_float4(0.f, 0.f, 0.f, 0.f);
    else                             v = *(const float4*)(src + e);
    ushort4 o;
    o.x = f2bf(v.x); o.y = f2bf(v.y); o.z = f2bf(v.z); o.w = f2bf(v.w);
    *(ushort4*)(dst + e) = o;
}

// ---------------------------------------------------------------------------
// Fused projection GEMMs (Q,K,Vt,pk,pq) in one launch. grid=(6,24,5).
// z=0: Q -> (B,H,S,64) bf16   z=1: K -> (B,H,S,64) bf16
// z=2: V -> (B,H,64,S) bf16 (TRANSPOSED for attention PV B-fragments)
// z=3: pk flat (768,768) bf16  z=4: pq flat bf16   (z>=3: only y<6 active)
// 128x128 tile, BK=32, 4 waves, mfma 16x16x32 bf16, global_load_lds staging.
// ---------------------------------------------------------------------------
__global__ __launch_bounds__(256) void proj_all(
    const unsigned short* __restrict__ xb, const unsigned short* __restrict__ relb,
    const unsigned short* __restrict__ wq, const unsigned short* __restrict__ wk,
    const unsigned short* __restrict__ wv, const unsigned short* __restrict__ wpk,
    const unsigned short* __restrict__ wpq,
    const float* __restrict__ bq, const float* __restrict__ bk,
    const float* __restrict__ bv, const float* __restrict__ bpk,
    const float* __restrict__ bpq,
    unsigned short* __restrict__ qb, unsigned short* __restrict__ kb,
    unsigned short* __restrict__ vtb, unsigned short* __restrict__ pkb,
    unsigned short* __restrict__ pqb)
{
    const int z = blockIdx.z;
    if (z >= 3 && blockIdx.y >= 6) return;

    const unsigned short* A = (z < 3) ? xb : relb;
    const unsigned short* W = (z == 0) ? wq : (z == 1) ? wk : (z == 2) ? wv
                            : (z == 3) ? wpk : wpq;
    const float* bias = (z == 0) ? bq : (z == 1) ? bk : (z == 2) ? bv
                      : (z == 3) ? bpk : bpq;
    unsigned short* C = (z == 0) ? qb : (z == 1) ? kb : (z == 2) ? vtb
                      : (z == 3) ? pkb : pqb;

    __shared__ unsigned short As[128 * 32];
    __shared__ unsigned short Ws[128 * 32];

    const int tid  = threadIdx.x;
    const int lane = tid & 63;
    const int wv_  = tid >> 6;
    const int wy   = wv_ >> 1, wx = wv_ & 1;
    const int quad = lane >> 4, l16 = lane & 15;
    const int m0 = blockIdx.y * 128, n0 = blockIdx.x * 128;

    floatx4 acc[4][4];
#pragma unroll
    for (int i = 0; i < 4; ++i)
#pragma unroll
        for (int j = 0; j < 4; ++j) acc[i][j] = (floatx4){0.f, 0.f, 0.f, 0.f};

    const int koff = quad * 8;

    for (int k0 = 0; k0 < 768; k0 += 32) {
        __syncthreads();
#pragma unroll
        for (int r = 0; r < 2; ++r) {
            int idx = tid + 256 * r;
            int row = idx >> 2, c8 = (idx & 3) * 8;
            const unsigned short* ga = A + (size_t)(m0 + row) * 768 + k0 + c8;
            const unsigned short* gw = W + (size_t)(n0 + row) * 768 + k0 + c8;
            __builtin_amdgcn_global_load_lds(
                (__attribute__((address_space(1))) void*)ga,
                (__attribute__((address_space(3))) void*)&As[idx * 8], 16, 0, 0);
            __builtin_amdgcn_global_load_lds(
                (__attribute__((address_space(1))) void*)gw,
                (__attribute__((address_space(3))) void*)&Ws[idx * 8], 16, 0, 0);
        }
        __syncthreads();

        bf16x8 a[4], b[4];
#pragma unroll
        for (int mi = 0; mi < 4; ++mi)
            a[mi] = __builtin_bit_cast(bf16x8,
                *(const ux4*)&As[(wy * 64 + mi * 16 + l16) * 32 + koff]);
#pragma unroll
        for (int ni = 0; ni < 4; ++ni)
            b[ni] = __builtin_bit_cast(bf16x8,
                *(const ux4*)&Ws[(wx * 64 + ni * 16 + l16) * 32 + koff]);
#pragma unroll
        for (int mi = 0; mi < 4; ++mi)
#pragma unroll
            for (int ni = 0; ni < 4; ++ni)
                acc[mi][ni] = __builtin_amdgcn_mfma_f32_16x16x32_bf16(
                    a[mi], b[ni], acc[mi][ni], 0, 0, 0);
    }

#pragma unroll
    for (int ni = 0; ni < 4; ++ni) {
        const int n = n0 + wx * 64 + ni * 16 + l16;
        const float bn = bias[n];
#pragma unroll
        for (int mi = 0; mi < 4; ++mi) {
            const int mbase = m0 + wy * 64 + mi * 16 + quad * 4;
            if (z == 2) {
                // Vt: addr = ((b*H+h)*64+hd)*384 + s, s = mbase+reg consecutive
                const int bb = mbase / S_, s = mbase - bb * S_;
                const int h = n >> 6, hd = n & 63;
                ushort4 o;
                o.x = f2bf(acc[mi][ni][0] + bn);
                o.y = f2bf(acc[mi][ni][1] + bn);
                o.z = f2bf(acc[mi][ni][2] + bn);
                o.w = f2bf(acc[mi][ni][3] + bn);
                *(ushort4*)&C[(((size_t)(bb * H_ + h) << 6) + hd) * S_ + s] = o;
            } else if (z < 2) {
#pragma unroll
                for (int reg = 0; reg < 4; ++reg) {
                    const int m = mbase + reg;
                    const int bb = m / S_, s = m - bb * S_;
                    const int h = n >> 6, hd = n & 63;
                    C[(((size_t)(bb * H_ + h) * S_ + s) << 6) + hd] =
                        f2bf(acc[mi][ni][reg] + bn);
                }
            } else {
#pragma unroll
                for (int reg = 0; reg < 4; ++reg)
                    C[(size_t)(mbase + reg) * 768 + n] = f2bf(acc[mi][ni][reg] + bn);
            }
        }
    }
}

// ---------------------------------------------------------------------------
// Output projection: fp32 out = valsb(bf16) @ Wo^T + bo. grid=(6,24).
// ---------------------------------------------------------------------------
__global__ __launch_bounds__(256) void gemm_out(
    const unsigned short* __restrict__ A, const unsigned short* __restrict__ W,
    const float* __restrict__ bias, float* __restrict__ C)
{
    __shared__ unsigned short As[128 * 32];
    __shared__ unsigned short Ws[128 * 32];

    const int tid  = threadIdx.x;
    const int lane = tid & 63;
    const int wv_  = tid >> 6;
    const int wy   = wv_ >> 1, wx = wv_ & 1;
    const int quad = lane >> 4, l16 = lane & 15;
    const int m0 = blockIdx.y * 128, n0 = blockIdx.x * 128;

    floatx4 acc[4][4];
#pragma unroll
    for (int i = 0; i < 4; ++i)
#pragma unroll
        for (int j = 0; j < 4; ++j) acc[i][j] = (floatx4){0.f, 0.f, 0.f, 0.f};

    const int koff = quad * 8;

    for (int k0 = 0; k0 < 768; k0 += 32) {
        __syncthreads();
#pragma unroll
        for (int r = 0; r < 2; ++r) {
            int idx = tid + 256 * r;
            int row = idx >> 2, c8 = (idx & 3) * 8;
            const unsigned short* ga = A + (size_t)(m0 + row) * 768 + k0 + c8;
            const unsigned short* gw = W + (size_t)(n0 + row) * 768 + k0 + c8;
            __builtin_amdgcn_global_load_lds(
                (__attribute__((address_space(1))) void*)ga,
                (__attribute__((address_space(3))) void*)&As[idx * 8], 16, 0, 0);
            __builtin_amdgcn_global_load_lds(
                (__attribute__((address_space(1))) void*)gw,
                (__attribute__((address_space(3))) void*)&Ws[idx * 8], 16, 0, 0);
        }
        __syncthreads();

        bf16x8 a[4], b[4];
#pragma unroll
        for (int mi = 0; mi < 4; ++mi)
            a[mi] = __builtin_bit_cast(bf16x8,
                *(const ux4*)&As[(wy * 64 + mi * 16 + l16) * 32 + koff]);
#pragma unroll
        for (int ni = 0; ni < 4; ++ni)
            b[ni] = __builtin_bit_cast(bf16x8,
                *(const ux4*)&Ws[(wx * 64 + ni * 16 + l16) * 32 + koff]);
#pragma unroll
        for (int mi = 0; mi < 4; ++mi)
#pragma unroll
            for (int ni = 0; ni < 4; ++ni)
                acc[mi][ni] = __builtin_amdgcn_mfma_f32_16x16x32_bf16(
                    a[mi], b[ni], acc[mi][ni], 0, 0, 0);
    }

#pragma unroll
    for (int ni = 0; ni < 4; ++ni) {
        const int n = n0 + wx * 64 + ni * 16 + l16;
        const float bn = bias[n];
#pragma unroll
        for (int mi = 0; mi < 4; ++mi)
#pragma unroll
            for (int reg = 0; reg < 4; ++reg) {
                const int m = m0 + wy * 64 + mi * 16 + quad * 4 + reg;
                C[(size_t)m * 768 + n] = acc[mi][ni][reg] + bn;
            }
    }
}

// ---------------------------------------------------------------------------
// MFMA flash attention. Block=(i-tile 64, h, b), 256 thr = 4 waves.
// Wave w owns ii strip [16w,16w+16). Per j-tile (64):
//   c2c : Q(reg) x Ks       -> S  (writes, full cover)
//   c2p : Q(reg) x PKs      -> atomicAdd S at jj = ii-ddloc+63  (5 banded frags)
//   p2c : Ks x PQs          -> atomicAdd S at ii = ddloc+jj-63  (5 banded frags)
//   scalar pass: bias + mask + online softmax -> P bf16 (aliases Ks)
//   PV  : P x Vts (V pre-transposed in global) -> O regs (C layout)
// S uses column swizzle jj ^ (((ii>>2)&1)<<4) so MFMA-epilogue scalar writes
// are 2-way max. bf16 LDS arrays padded to 72 shorts/row (144B: 16B-aligned,
// 4-bank advance/row -> <=2-way on ds_read_b128).
// LDS total ~73.4 KB -> 2 blocks/CU.
// ---------------------------------------------------------------------------
#define PAD 72

__global__ __launch_bounds__(256) void attn_mfma(
    const unsigned short* __restrict__ qg, const unsigned short* __restrict__ kg,
    const unsigned short* __restrict__ vtg,
    const unsigned short* __restrict__ pkg, const unsigned short* __restrict__ pqg,
    const int* __restrict__ seg, const float* __restrict__ sep,
    const int* __restrict__ mask,
    const float* __restrict__ same_bias, const float* __restrict__ cross_bias,
    const float* __restrict__ sep_scale, const float* __restrict__ sep_decay,
    unsigned short* __restrict__ vals)
{
    __shared__ unsigned short KsPs[64 * PAD];   // K tile; aliased as P after use
    __shared__ unsigned short Vts[64 * PAD];    // V^T tile [d][jj]
    __shared__ unsigned short PKs[127 * PAD];   // pk rows [ddloc][d]
    __shared__ unsigned short PQs[127 * PAD];
    __shared__ float S[64 * 64];
    __shared__ float alpha_s[64], m_s[64], l_s[64];
    __shared__ float ai_s[64], aj_s[64];
    __shared__ int   si_s[64], sj_s[64], mj_s[64];

    const int tid  = threadIdx.x;
    const int lane = tid & 63, w = tid >> 6;
    const int l16  = lane & 15, quad = lane >> 4;
    const int ty = tid >> 4, tx = tid & 15;
    const int it = blockIdx.x, h = blockIdx.y, b = blockIdx.z;
    const int i0 = it * 64;
    const size_t bh = (size_t)(b * H_ + h);

    const unsigned short* kbase  = kg  + bh * S_ * 64;
    const unsigned short* vtbase = vtg + bh * 64 * S_;

    // Q fragments in registers for all 6 j-tiles: rows 16w+l16, ks 0/1
    bf16x8 qf[2];
#pragma unroll
    for (int ks = 0; ks < 2; ++ks)
        qf[ks] = __builtin_bit_cast(bf16x8,
            *(const ux4*)(qg + (bh * S_ + i0 + 16 * w + l16) * 64 + ks * 32 + quad * 8));

    if (tid < 64) {
        m_s[tid] = -INFINITY; l_s[tid] = 0.f;
        ai_s[tid] = fabsf(sep[b * S_ + i0 + tid]);
        si_s[tid] = seg[b * S_ + i0 + tid];
    }

    const float sb  = same_bias[h];
    const float cb  = cross_bias[h];
    const float ssc = sep_scale[h];
    const float sd  = sep_decay[h];
    const float dec = fmaxf(sd, 0.f) + log1pf(__expf(-fabsf(sd))) + 1e-4f;
    const float isc = 0.07216878364870323f;   // 1/sqrt(64*3)

    floatx4 O[4];
#pragma unroll
    for (int nd = 0; nd < 4; ++nd) O[nd] = (floatx4){0.f, 0.f, 0.f, 0.f};

    for (int jt = 0; jt < 6; ++jt) {
        const int j0 = jt * 64;
        __syncthreads();   // prev PV done; safe to overwrite staging

        // ---- stage K, Vt (64 rows x 8 chunks of 16B each) ----
#pragma unroll
        for (int r = 0; r < 2; ++r) {
            const int idx = tid + 256 * r;
            const int row = idx >> 3, c8 = (idx & 7) * 8;
            *(ux4*)&KsPs[row * PAD + c8] =
                *(const ux4*)(kbase + (size_t)(j0 + row) * 64 + c8);
            *(ux4*)&Vts[row * PAD + c8] =
                *(const ux4*)(vtbase + (size_t)row * S_ + j0 + c8);
        }
        // ---- stage pk/pq rows dbase..dbase+126 ----
        const int dbase = i0 - j0 + 320;
#pragma unroll
        for (int r = 0; r < 4; ++r) {
            const int idx = tid + 256 * r;
            if (idx < 127 * 8) {
                const int row = idx >> 3, c8 = (idx & 7) * 8;
                const size_t go = (size_t)(dbase + row) * 768 + h * 64 + c8;
                *(ux4*)&PKs[row * PAD + c8] = *(const ux4*)(pkg + go);
                *(ux4*)&PQs[row * PAD + c8] = *(const ux4*)(pqg + go);
            }
        }
        if (tid < 64) {
            aj_s[tid] = fabsf(sep[b * S_ + j0 + tid]);
            sj_s[tid] = seg[b * S_ + j0 + tid];
            mj_s[tid] = mask[b * S_ + j0 + tid];
        }
        __syncthreads();

        // ---- c2c: S[ii][jj] = q_ii . k_jj ----
#pragma unroll
        for (int nj = 0; nj < 4; ++nj) {
            floatx4 acc = (floatx4){0.f, 0.f, 0.f, 0.f};
#pragma unroll
            for (int ks = 0; ks < 2; ++ks) {
                bf16x8 bf = __builtin_bit_cast(bf16x8,
                    *(const ux4*)&KsPs[(16 * nj + l16) * PAD + ks * 32 + quad * 8]);
                acc = __builtin_amdgcn_mfma_f32_16x16x32_bf16(qf[ks], bf, acc, 0, 0, 0);
            }
            const int jj = 16 * nj + l16;
#pragma unroll
            for (int reg = 0; reg < 4; ++reg) {
                const int ii = 16 * w + quad * 4 + reg;
                S[ii * 64 + (jj ^ ((quad & 1) << 4))] = acc[reg];
            }
        }
        __syncthreads();

        // ---- c2p: banded frags nd = w..w+4; scatter at jj = ii-ddloc+63 ----
#pragma unroll
        for (int f = 0; f < 5; ++f) {
            const int nd = w + f;
            floatx4 acc = (floatx4){0.f, 0.f, 0.f, 0.f};
#pragma unroll
            for (int ks = 0; ks < 2; ++ks) {
                bf16x8 bf = __builtin_bit_cast(bf16x8,
                    *(const ux4*)&PKs[(16 * nd + l16) * PAD + ks * 32 + quad * 8]);
                acc = __builtin_amdgcn_mfma_f32_16x16x32_bf16(qf[ks], bf, acc, 0, 0, 0);
            }
            const int ddloc = 16 * nd + l16;
#pragma unroll
            for (int reg = 0; reg < 4; ++reg) {
                const int ii = 16 * w + quad * 4 + reg;
                const int jj = ii - ddloc + 63;
                if (jj >= 0 && jj < 64)
                    atomicAdd(&S[ii * 64 + (jj ^ ((quad & 1) << 4))], acc[reg]);
            }
        }
        // ---- p2c: A = K rows (wave strip), banded frags nd = 3-w..7-w ----
        bf16x8 kfA[2];
#pragma unroll
        for (int ks = 0; ks < 2; ++ks)
            kfA[ks] = __builtin_bit_cast(bf16x8,
                *(const ux4*)&KsPs[(16 * w + l16) * PAD + ks * 32 + quad * 8]);
#pragma unroll
        for (int f = 0; f < 5; ++f) {
            const int nd = 3 - w + f;
            floatx4 acc = (floatx4){0.f, 0.f, 0.f, 0.f};
#pragma unroll
            for (int ks = 0; ks < 2; ++ks) {
                bf16x8 bf = __builtin_bit_cast(bf16x8,
                    *(const ux4*)&PQs[(16 * nd + l16) * PAD + ks * 32 + quad * 8]);
                acc = __builtin_amdgcn_mfma_f32_16x16x32_bf16(kfA[ks], bf, acc, 0, 0, 0);
            }
            const int ddloc = 16 * nd + l16;
#pragma unroll
            for (int reg = 0; reg < 4; ++reg) {
                const int jj = 16 * w + quad * 4 + reg;
                const int ii = ddloc + jj - 63;
                if (ii >= 0 && ii < 64)
                    atomicAdd(&S[ii * 64 + (jj ^ (((ii >> 2) & 1) << 4))], acc[reg]);
            }
        }
        __syncthreads();

        // ---- scalar pass: bias + mask + online softmax; P -> KsPs (bf16) ----
#pragma unroll
        for (int p = 0; p < 4; ++p) {
            const int ii = 4 * ty + p;
            const float aii = ai_s[ii];
            const int   sii = si_s[ii];
            const int sbit = (ty & 1) << 4;
            float lg[4];
            float tmax = -INFINITY;
#pragma unroll
            for (int r = 0; r < 4; ++r) {
                const int jl = 4 * tx + r;
                float xv = S[ii * 64 + (jl ^ sbit)] * isc;
                const float gap = fabsf(aii - aj_s[jl]);
                const float bias = (sii == sj_s[jl]) ? sb
                                 : cb + __expf(-gap * dec) * ssc;
                xv += bias;
                if (mj_s[jl] == 0) xv = -9.0e15f;
                lg[r] = xv;
                tmax = fmaxf(tmax, xv);
            }
#pragma unroll
            for (int off = 1; off < 16; off <<= 1)
                tmax = fmaxf(tmax, __shfl_xor(tmax, off));
            const float mp = m_s[ii];
            const float nm = fmaxf(mp, tmax);
            const float alpha = __expf(mp - nm);
            float rs = 0.f;
            ushort4 pw;
#pragma unroll
            for (int r = 0; r < 4; ++r) {
                const float e = __expf(lg[r] - nm);
                rs += e;
                ((unsigned short*)&pw)[r] = f2bf(e);
            }
#pragma unroll
            for (int off = 1; off < 16; off <<= 1)
                rs += __shfl_xor(rs, off);
            if (tx == 0) {
                m_s[ii] = nm;
                alpha_s[ii] = alpha;
                l_s[ii] = l_s[ii] * alpha + rs;
            }
            *(ushort4*)&KsPs[ii * PAD + 4 * tx] = pw;
        }
        __syncthreads();

        // ---- PV: O[ii][d] = sum_jj P[ii][jj] * Vt[d][jj] ----
        float av[4];
#pragma unroll
        for (int reg = 0; reg < 4; ++reg)
            av[reg] = alpha_s[16 * w + quad * 4 + reg];
        bf16x8 pA[2];
#pragma unroll
        for (int ks = 0; ks < 2; ++ks)
            pA[ks] = __builtin_bit_cast(bf16x8,
                *(const ux4*)&KsPs[(16 * w + l16) * PAD + ks * 32 + quad * 8]);
#pragma unroll
        for (int nd = 0; nd < 4; ++nd) {
#pragma unroll
            for (int reg = 0; reg < 4; ++reg) O[nd][reg] *= av[reg];
#pragma unroll
            for (int ks = 0; ks < 2; ++ks) {
                bf16x8 bf = __builtin_bit_cast(bf16x8,
                    *(const ux4*)&Vts[(16 * nd + l16) * PAD + ks * 32 + quad * 8]);
                O[nd] = __builtin_amdgcn_mfma_f32_16x16x32_bf16(pA[ks], bf, O[nd], 0, 0, 0);
            }
        }
    }

    // ---- epilogue: normalize, write bf16 vals (B,S,E) ----
#pragma unroll
    for (int nd = 0; nd < 4; ++nd) {
        const int d = 16 * nd + l16;
#pragma unroll
        for (int reg = 0; reg < 4; ++reg) {
            const int ii = 16 * w + quad * 4 + reg;
            const float val = O[nd][reg] / l_s[ii];
            vals[((size_t)(b * S_ + i0 + ii)) * E_ + h * 64 + d] = f2bf(val);
        }
    }
}

// ---------------------------------------------------------------------------
// Launcher. Workspace (bf16 shorts): xb 2359296; wqb..wpqb+relb 7x589824;
// qb,kb,vtb 3x2359296; pkb,pqb 2x589824 (768 rows); valsb 2359296. ~34.2 MB.
// ---------------------------------------------------------------------------
extern "C" void kernel_launch(void* const* d_in, const int* in_sizes, int n_in,
                              void* d_out, int out_size, void* d_ws, size_t ws_size,
                              hipStream_t stream)
{
    const float* x         = (const float*)d_in[0];
    const int*   mask      = (const int*)d_in[1];
    const int*   seg       = (const int*)d_in[2];
    const float* sep       = (const float*)d_in[3];
    const float* Wq        = (const float*)d_in[4];
    const float* bq        = (const float*)d_in[5];
    const float* Wk        = (const float*)d_in[6];
    const float* bk        = (const float*)d_in[7];
    const float* Wv        = (const float*)d_in[8];
    const float* bv        = (const float*)d_in[9];
    const float* rel_emb   = (const float*)d_in[10];
    const float* Wpk       = (const float*)d_in[11];
    const float* bpk       = (const float*)d_in[12];
    const float* Wpq       = (const float*)d_in[13];
    const float* bpq       = (const float*)d_in[14];
    const float* same_bias = (const float*)d_in[15];
    const float* cross_bias= (const float*)d_in[16];
    const float* sep_scale = (const float*)d_in[17];
    const float* sep_decay = (const float*)d_in[18];
    const float* Wo        = (const float*)d_in[19];
    const float* bo        = (const float*)d_in[20];

    const size_t QKVN = (size_t)B_ * S_ * E_;   // 2359296
    const size_t WN   = (size_t)768 * 768;      //  589824

    unsigned short* xb    = (unsigned short*)d_ws;
    unsigned short* wqb   = xb   + QKVN;
    unsigned short* wkb   = wqb  + WN;
    unsigned short* wvb   = wkb  + WN;
    unsigned short* wob   = wvb  + WN;
    unsigned short* wpkb  = wob  + WN;
    unsigned short* wpqb  = wpkb + WN;
    unsigned short* relb  = wpqb + WN;
    unsigned short* qb    = relb + WN;
    unsigned short* kb    = qb   + QKVN;
    unsigned short* vtb   = kb   + QKVN;
    unsigned short* pkb   = vtb  + QKVN;
    unsigned short* pqb   = pkb  + WN;
    unsigned short* valsb = pqb  + WN;

    // 1) convert all operands to bf16
    convert_all<<<dim3(576, 11), 256, 0, stream>>>(
        x, Wq, Wk, Wv, Wo, Wpk, Wpq, rel_emb + (size_t)128 * D_,
        xb, wqb, wkb, wvb, wob, wpkb, wpqb, relb);

    // 2) fused Q/K/Vt/pk/pq projections
    proj_all<<<dim3(6, 24, 5), 256, 0, stream>>>(
        xb, relb, wqb, wkb, wvb, wpkb, wpqb,
        bq, bk, bv, bpk, bpq, qb, kb, vtb, pkb, pqb);

    // 3) MFMA flash attention
    attn_mfma<<<dim3(S_ / 64, H_, B_), 256, 0, stream>>>(
        qb, kb, vtb, pkb, pqb, seg, sep, mask,
        same_bias, cross_bias, sep_scale, sep_decay, valsb);

    // 4) output projection
    gemm_out<<<dim3(6, 24), 256, 0, stream>>>(valsb, wob, bo, (float*)d_out);
}

// Round 5
// 292.668 us; speedup vs baseline: 12.4228x; 1.4386x over previous
//
#include <hip/hip_runtime.h>
#include <math.h>

// Problem constants
#define B_  8
#define S_  384
#define H_  12
#define HD_ 64
#define E_  768
#define D_  768

typedef float  floatx4 __attribute__((ext_vector_type(4)));
typedef __bf16 bf16x8  __attribute__((ext_vector_type(8)));
typedef unsigned int ux4 __attribute__((ext_vector_type(4)));

__device__ __forceinline__ unsigned short f2bf(float f) {
    union { float f; unsigned u; } x; x.f = f;
    unsigned r = x.u + 0x7fff + ((x.u >> 16) & 1);
    return (unsigned short)(r >> 16);
}

__device__ __forceinline__ bf16x8 gld8(const unsigned short* p) {
    return __builtin_bit_cast(bf16x8, *(const ux4*)p);
}

// ---------------------------------------------------------------------------
// Fused fp32 -> bf16 convert. grid=(576,11); 1024 floats per block-segment.
// ---------------------------------------------------------------------------
__global__ __launch_bounds__(256) void convert_all(
    const float* __restrict__ x,
    const float* __restrict__ Wq, const float* __restrict__ Wk,
    const float* __restrict__ Wv, const float* __restrict__ Wo,
    const float* __restrict__ Wpk, const float* __restrict__ Wpq,
    const float* __restrict__ rel128,
    unsigned short* __restrict__ xb,
    unsigned short* __restrict__ wqb, unsigned short* __restrict__ wkb,
    unsigned short* __restrict__ wvb, unsigned short* __restrict__ wob,
    unsigned short* __restrict__ wpkb, unsigned short* __restrict__ wpqb,
    unsigned short* __restrict__ relb)
{
    const int seg = blockIdx.y;
    const int e = (blockIdx.x * 256 + threadIdx.x) * 4;
    const float* src;
    unsigned short* dst;
    if (seg < 4)       { src = x + (size_t)seg * 589824; dst = xb + (size_t)seg * 589824; }
    else if (seg == 4) { src = Wq;  dst = wqb; }
    else if (seg == 5) { src = Wk;  dst = wkb; }
    else if (seg == 6) { src = Wv;  dst = wvb; }
    else if (seg == 7) { src = Wo;  dst = wob; }
    else if (seg == 8) { src = Wpk; dst = wpkb; }
    else if (seg == 9) { src = Wpq; dst = wpqb; }
    else               { src = rel128; dst = relb; }

    float4 v;
    if (seg == 10 && e >= 767 * 768) v = make_float4(0.f, 0.f, 0.f, 0.f);
    else                             v = *(const float4*)(src + e);
    ushort4 o;
    o.x = f2bf(v.x); o.y = f2bf(v.y); o.z = f2bf(v.z); o.w = f2bf(v.w);
    *(ushort4*)(dst + e) = o;
}

// ---------------------------------------------------------------------------
// Fused projection GEMMs (Q,K,Vt,pk,pq) in one launch. grid=(6,24,5).
// ---------------------------------------------------------------------------
__global__ __launch_bounds__(256) void proj_all(
    const unsigned short* __restrict__ xb, const unsigned short* __restrict__ relb,
    const unsigned short* __restrict__ wq, const unsigned short* __restrict__ wk,
    const unsigned short* __restrict__ wv, const unsigned short* __restrict__ wpk,
    const unsigned short* __restrict__ wpq,
    const float* __restrict__ bq, const float* __restrict__ bk,
    const float* __restrict__ bv, const float* __restrict__ bpk,
    const float* __restrict__ bpq,
    unsigned short* __restrict__ qb, unsigned short* __restrict__ kb,
    unsigned short* __restrict__ vtb, unsigned short* __restrict__ pkb,
    unsigned short* __restrict__ pqb)
{
    const int z = blockIdx.z;
    if (z >= 3 && blockIdx.y >= 6) return;

    const unsigned short* A = (z < 3) ? xb : relb;
    const unsigned short* W = (z == 0) ? wq : (z == 1) ? wk : (z == 2) ? wv
                            : (z == 3) ? wpk : wpq;
    const float* bias = (z == 0) ? bq : (z == 1) ? bk : (z == 2) ? bv
                      : (z == 3) ? bpk : bpq;
    unsigned short* C = (z == 0) ? qb : (z == 1) ? kb : (z == 2) ? vtb
                      : (z == 3) ? pkb : pqb;

    __shared__ unsigned short As[128 * 32];
    __shared__ unsigned short Ws[128 * 32];

    const int tid  = threadIdx.x;
    const int lane = tid & 63;
    const int wv_  = tid >> 6;
    const int wy   = wv_ >> 1, wx = wv_ & 1;
    const int quad = lane >> 4, l16 = lane & 15;
    const int m0 = blockIdx.y * 128, n0 = blockIdx.x * 128;

    floatx4 acc[4][4];
#pragma unroll
    for (int i = 0; i < 4; ++i)
#pragma unroll
        for (int j = 0; j < 4; ++j) acc[i][j] = (floatx4){0.f, 0.f, 0.f, 0.f};

    const int koff = quad * 8;

    for (int k0 = 0; k0 < 768; k0 += 32) {
        __syncthreads();
#pragma unroll
        for (int r = 0; r < 2; ++r) {
            int idx = tid + 256 * r;
            int row = idx >> 2, c8 = (idx & 3) * 8;
            const unsigned short* ga = A + (size_t)(m0 + row) * 768 + k0 + c8;
            const unsigned short* gw = W + (size_t)(n0 + row) * 768 + k0 + c8;
            __builtin_amdgcn_global_load_lds(
                (__attribute__((address_space(1))) void*)ga,
                (__attribute__((address_space(3))) void*)&As[idx * 8], 16, 0, 0);
            __builtin_amdgcn_global_load_lds(
                (__attribute__((address_space(1))) void*)gw,
                (__attribute__((address_space(3))) void*)&Ws[idx * 8], 16, 0, 0);
        }
        __syncthreads();

        bf16x8 a[4], b[4];
#pragma unroll
        for (int mi = 0; mi < 4; ++mi)
            a[mi] = __builtin_bit_cast(bf16x8,
                *(const ux4*)&As[(wy * 64 + mi * 16 + l16) * 32 + koff]);
#pragma unroll
        for (int ni = 0; ni < 4; ++ni)
            b[ni] = __builtin_bit_cast(bf16x8,
                *(const ux4*)&Ws[(wx * 64 + ni * 16 + l16) * 32 + koff]);
#pragma unroll
        for (int mi = 0; mi < 4; ++mi)
#pragma unroll
            for (int ni = 0; ni < 4; ++ni)
                acc[mi][ni] = __builtin_amdgcn_mfma_f32_16x16x32_bf16(
                    a[mi], b[ni], acc[mi][ni], 0, 0, 0);
    }

#pragma unroll
    for (int ni = 0; ni < 4; ++ni) {
        const int n = n0 + wx * 64 + ni * 16 + l16;
        const float bn = bias[n];
#pragma unroll
        for (int mi = 0; mi < 4; ++mi) {
            const int mbase = m0 + wy * 64 + mi * 16 + quad * 4;
            if (z == 2) {
                const int bb = mbase / S_, s = mbase - bb * S_;
                const int h = n >> 6, hd = n & 63;
                ushort4 o;
                o.x = f2bf(acc[mi][ni][0] + bn);
                o.y = f2bf(acc[mi][ni][1] + bn);
                o.z = f2bf(acc[mi][ni][2] + bn);
                o.w = f2bf(acc[mi][ni][3] + bn);
                *(ushort4*)&C[(((size_t)(bb * H_ + h) << 6) + hd) * S_ + s] = o;
            } else if (z < 2) {
#pragma unroll
                for (int reg = 0; reg < 4; ++reg) {
                    const int m = mbase + reg;
                    const int bb = m / S_, s = m - bb * S_;
                    const int h = n >> 6, hd = n & 63;
                    C[(((size_t)(bb * H_ + h) * S_ + s) << 6) + hd] =
                        f2bf(acc[mi][ni][reg] + bn);
                }
            } else {
#pragma unroll
                for (int reg = 0; reg < 4; ++reg)
                    C[(size_t)(mbase + reg) * 768 + n] = f2bf(acc[mi][ni][reg] + bn);
            }
        }
    }
}

// ---------------------------------------------------------------------------
// Output projection: fp32 out = valsb(bf16) @ Wo^T + bo. grid=(6,24).
// ---------------------------------------------------------------------------
__global__ __launch_bounds__(256) void gemm_out(
    const unsigned short* __restrict__ A, const unsigned short* __restrict__ W,
    const float* __restrict__ bias, float* __restrict__ C)
{
    __shared__ unsigned short As[128 * 32];
    __shared__ unsigned short Ws[128 * 32];

    const int tid  = threadIdx.x;
    const int lane = tid & 63;
    const int wv_  = tid >> 6;
    const int wy   = wv_ >> 1, wx = wv_ & 1;
    const int quad = lane >> 4, l16 = lane & 15;
    const int m0 = blockIdx.y * 128, n0 = blockIdx.x * 128;

    floatx4 acc[4][4];
#pragma unroll
    for (int i = 0; i < 4; ++i)
#pragma unroll
        for (int j = 0; j < 4; ++j) acc[i][j] = (floatx4){0.f, 0.f, 0.f, 0.f};

    const int koff = quad * 8;

    for (int k0 = 0; k0 < 768; k0 += 32) {
        __syncthreads();
#pragma unroll
        for (int r = 0; r < 2; ++r) {
            int idx = tid + 256 * r;
            int row = idx >> 2, c8 = (idx & 3) * 8;
            const unsigned short* ga = A + (size_t)(m0 + row) * 768 + k0 + c8;
            const unsigned short* gw = W + (size_t)(n0 + row) * 768 + k0 + c8;
            __builtin_amdgcn_global_load_lds(
                (__attribute__((address_space(1))) void*)ga,
                (__attribute__((address_space(3))) void*)&As[idx * 8], 16, 0, 0);
            __builtin_amdgcn_global_load_lds(
                (__attribute__((address_space(1))) void*)gw,
                (__attribute__((address_space(3))) void*)&Ws[idx * 8], 16, 0, 0);
        }
        __syncthreads();

        bf16x8 a[4], b[4];
#pragma unroll
        for (int mi = 0; mi < 4; ++mi)
            a[mi] = __builtin_bit_cast(bf16x8,
                *(const ux4*)&As[(wy * 64 + mi * 16 + l16) * 32 + koff]);
#pragma unroll
        for (int ni = 0; ni < 4; ++ni)
            b[ni] = __builtin_bit_cast(bf16x8,
                *(const ux4*)&Ws[(wx * 64 + ni * 16 + l16) * 32 + koff]);
#pragma unroll
        for (int mi = 0; mi < 4; ++mi)
#pragma unroll
            for (int ni = 0; ni < 4; ++ni)
                acc[mi][ni] = __builtin_amdgcn_mfma_f32_16x16x32_bf16(
                    a[mi], b[ni], acc[mi][ni], 0, 0, 0);
    }

#pragma unroll
    for (int ni = 0; ni < 4; ++ni) {
        const int n = n0 + wx * 64 + ni * 16 + l16;
        const float bn = bias[n];
#pragma unroll
        for (int mi = 0; mi < 4; ++mi)
#pragma unroll
            for (int reg = 0; reg < 4; ++reg) {
                const int m = m0 + wy * 64 + mi * 16 + quad * 4 + reg;
                C[(size_t)m * 768 + n] = acc[mi][ni][reg] + bn;
            }
    }
}

// ---------------------------------------------------------------------------
// MFMA flash attention v3 — no LDS staging, no LDS atomics, 2 barriers/j-tile.
// Block=(i-tile 64, h, b), 256 thr = 4 waves; wave w owns row strip
// ii in [16w,16w+16). MFMA B-fragments load DIRECTLY from global (dwordx4;
// L1/L2 serve the reuse). LDS only: CP (fp32 64x68 score tile), Pp (bf16 P),
// per-row state. Phase layout per j-tile:
//   A: c2c (stores CP rows strip w) + c2p banded RMW (same rows) [wave-private]
//   B1; p2c banded RMW (cols strip w, reads other waves' rows)
//   B2; softmax (rows strip w) + PV (rows strip w)   [wave-private, no barrier]
// j-side metadata (aj/sj/mj) parity-double-buffered across j-tiles.
// LDS ~29 KB -> 5 blocks/CU capacity.
// ---------------------------------------------------------------------------
__global__ __launch_bounds__(256) void attn_mfma(
    const unsigned short* __restrict__ qg, const unsigned short* __restrict__ kg,
    const unsigned short* __restrict__ vtg,
    const unsigned short* __restrict__ pkg, const unsigned short* __restrict__ pqg,
    const int* __restrict__ seg, const float* __restrict__ sep,
    const int* __restrict__ mask,
    const float* __restrict__ same_bias, const float* __restrict__ cross_bias,
    const float* __restrict__ sep_scale, const float* __restrict__ sep_decay,
    unsigned short* __restrict__ vals)
{
    __shared__ float CP[64 * 68];              // fp32 score tile, pitch 68
    __shared__ unsigned short Pp[64 * 72];     // bf16 P, pitch 72
    __shared__ float alpha_s[64], m_s[64], l_s[64], ai_s[64];
    __shared__ int   si_s[64];
    __shared__ float aj_s[2][64];
    __shared__ int   sj_s[2][64], mj_s[2][64];

    const int tid  = threadIdx.x;
    const int lane = tid & 63, w = tid >> 6;
    const int l16  = lane & 15, quad = lane >> 4;
    const int ty = tid >> 4, tx = tid & 15;
    const int it = blockIdx.x, h = blockIdx.y, b = blockIdx.z;
    const int i0 = it * 64;
    const size_t bh = (size_t)(b * H_ + h);

    const unsigned short* kbase  = kg  + bh * S_ * 64;
    const unsigned short* vtbase = vtg + bh * 64 * S_;

    // Q A-fragments in registers (strip w), held for all 6 j-tiles
    bf16x8 qf[2];
#pragma unroll
    for (int ks = 0; ks < 2; ++ks)
        qf[ks] = gld8(qg + (bh * S_ + i0 + 16 * w + l16) * 64 + ks * 32 + quad * 8);

    // per-row state init — wave-private rows (lane<16 of wave w inits strip w)
    if (lane < 16) {
        const int ii = 16 * w + lane;
        m_s[ii] = -INFINITY; l_s[ii] = 0.f;
        ai_s[ii] = fabsf(sep[b * S_ + i0 + ii]);
        si_s[ii] = seg[b * S_ + i0 + ii];
    }

    const float sb  = same_bias[h];
    const float cb  = cross_bias[h];
    const float ssc = sep_scale[h];
    const float sd  = sep_decay[h];
    const float dec = fmaxf(sd, 0.f) + log1pf(__expf(-fabsf(sd))) + 1e-4f;
    const float isc = 0.07216878364870323f;   // 1/sqrt(64*3)

    floatx4 O[4];
#pragma unroll
    for (int nd = 0; nd < 4; ++nd) O[nd] = (floatx4){0.f, 0.f, 0.f, 0.f};

    for (int jt = 0; jt < 6; ++jt) {
        const int j0 = jt * 64;
        const int pr = jt & 1;
        const int dbase = i0 - j0 + 320;    // pk/pq row window base (0..640)

        // j-side metadata for this tile (parity buffer; wave w covers cols strip w)
        if (lane < 16) {
            const int jj = 16 * w + lane;
            aj_s[pr][jj] = fabsf(sep[b * S_ + j0 + jj]);
            sj_s[pr][jj] = seg[b * S_ + j0 + jj];
            mj_s[pr][jj] = mask[b * S_ + j0 + jj];
        }

        // ---- phase A (wave-private rows strip w): c2c store + c2p RMW ----
#pragma unroll
        for (int nj = 0; nj < 4; ++nj) {
            floatx4 acc = (floatx4){0.f, 0.f, 0.f, 0.f};
#pragma unroll
            for (int ks = 0; ks < 2; ++ks) {
                bf16x8 bf = gld8(kbase + (size_t)(j0 + 16 * nj + l16) * 64 + ks * 32 + quad * 8);
                acc = __builtin_amdgcn_mfma_f32_16x16x32_bf16(qf[ks], bf, acc, 0, 0, 0);
            }
#pragma unroll
            for (int reg = 0; reg < 4; ++reg) {
                const int ii = 16 * w + quad * 4 + reg;
                CP[ii * 68 + 16 * nj + l16] = acc[reg];
            }
        }
        __asm__ volatile("s_waitcnt lgkmcnt(0)" ::: "memory");
#pragma unroll
        for (int f = 0; f < 5; ++f) {
            const int nd = w + f;
            floatx4 acc = (floatx4){0.f, 0.f, 0.f, 0.f};
#pragma unroll
            for (int ks = 0; ks < 2; ++ks) {
                bf16x8 bf = gld8(pkg + (size_t)(dbase + 16 * nd + l16) * 768 + h * 64 + ks * 32 + quad * 8);
                acc = __builtin_amdgcn_mfma_f32_16x16x32_bf16(qf[ks], bf, acc, 0, 0, 0);
            }
            const int ddloc = 16 * nd + l16;
#pragma unroll
            for (int reg = 0; reg < 4; ++reg) {
                const int ii = 16 * w + quad * 4 + reg;
                const int jj = ii - ddloc + 63;
                if (jj >= 0 && jj < 64)
                    CP[ii * 68 + jj] += acc[reg];     // unique writer per cell
            }
        }
        __syncthreads();   // B1: rows complete, expose to column-band phase

        // ---- p2c (cols strip w): A = K rows strip w, banded RMW ----
        bf16x8 kfA[2];
#pragma unroll
        for (int ks = 0; ks < 2; ++ks)
            kfA[ks] = gld8(kbase + (size_t)(j0 + 16 * w + l16) * 64 + ks * 32 + quad * 8);
#pragma unroll
        for (int f = 0; f < 5; ++f) {
            const int nd = 3 - w + f;
            floatx4 acc = (floatx4){0.f, 0.f, 0.f, 0.f};
#pragma unroll
            for (int ks = 0; ks < 2; ++ks) {
                bf16x8 bf = gld8(pqg + (size_t)(dbase + 16 * nd + l16) * 768 + h * 64 + ks * 32 + quad * 8);
                acc = __builtin_amdgcn_mfma_f32_16x16x32_bf16(kfA[ks], bf, acc, 0, 0, 0);
            }
            const int ddloc = 16 * nd + l16;
#pragma unroll
            for (int reg = 0; reg < 4; ++reg) {
                const int jj = 16 * w + quad * 4 + reg;
                const int ii = ddloc + jj - 63;
                if (ii >= 0 && ii < 64)
                    CP[ii * 68 + jj] += acc[reg];     // unique writer per cell
            }
        }
        __syncthreads();   // B2: full score tile ready

        // ---- softmax (wave-private rows strip w; thread ty covers 4ty..) ----
#pragma unroll
        for (int p = 0; p < 4; ++p) {
            const int ii = 4 * ty + p;
            const float aii = ai_s[ii];
            const int   sii = si_s[ii];
            float lg[4];
            float tmax = -INFINITY;
#pragma unroll
            for (int r = 0; r < 4; ++r) {
                const int jl = 4 * tx + r;
                float xv = CP[ii * 68 + jl] * isc;
                const float gap = fabsf(aii - aj_s[pr][jl]);
                const float bias = (sii == sj_s[pr][jl]) ? sb
                                 : cb + __expf(-gap * dec) * ssc;
                xv += bias;
                if (mj_s[pr][jl] == 0) xv = -9.0e15f;
                lg[r] = xv;
                tmax = fmaxf(tmax, xv);
            }
#pragma unroll
            for (int off = 1; off < 16; off <<= 1)
                tmax = fmaxf(tmax, __shfl_xor(tmax, off));
            const float mp = m_s[ii];
            const float nm = fmaxf(mp, tmax);
            const float alpha = __expf(mp - nm);
            float rs = 0.f;
            ushort4 pw;
#pragma unroll
            for (int r = 0; r < 4; ++r) {
                const float e = __expf(lg[r] - nm);
                rs += e;
                ((unsigned short*)&pw)[r] = f2bf(e);
            }
#pragma unroll
            for (int off = 1; off < 16; off <<= 1)
                rs += __shfl_xor(rs, off);
            if (tx == 0) {
                m_s[ii] = nm;
                alpha_s[ii] = alpha;
                l_s[ii] = l_s[ii] * alpha + rs;
            }
            *(ushort4*)&Pp[ii * 72 + 4 * tx] = pw;
        }
        __asm__ volatile("s_waitcnt lgkmcnt(0)" ::: "memory");

        // ---- PV (wave-private): O += P(strip w) x Vt ----
        float av[4];
#pragma unroll
        for (int reg = 0; reg < 4; ++reg)
            av[reg] = alpha_s[16 * w + quad * 4 + reg];
        bf16x8 pA[2];
#pragma unroll
        for (int ks = 0; ks < 2; ++ks)
            pA[ks] = __builtin_bit_cast(bf16x8,
                *(const ux4*)&Pp[(16 * w + l16) * 72 + ks * 32 + quad * 8]);
#pragma unroll
        for (int nd = 0; nd < 4; ++nd) {
#pragma unroll
            for (int reg = 0; reg < 4; ++reg) O[nd][reg] *= av[reg];
#pragma unroll
            for (int ks = 0; ks < 2; ++ks) {
                bf16x8 bf = gld8(vtbase + (size_t)(16 * nd + l16) * S_ + j0 + ks * 32 + quad * 8);
                O[nd] = __builtin_amdgcn_mfma_f32_16x16x32_bf16(pA[ks], bf, O[nd], 0, 0, 0);
            }
        }
        // no barrier: next phase A touches only wave-private rows of CP/Pp
    }

    // ---- epilogue: normalize, write bf16 vals (B,S,E) ----
#pragma unroll
    for (int nd = 0; nd < 4; ++nd) {
        const int d = 16 * nd + l16;
#pragma unroll
        for (int reg = 0; reg < 4; ++reg) {
            const int ii = 16 * w + quad * 4 + reg;
            const float val = O[nd][reg] / l_s[ii];
            vals[((size_t)(b * S_ + i0 + ii)) * E_ + h * 64 + d] = f2bf(val);
        }
    }
}

// ---------------------------------------------------------------------------
// Launcher. Workspace (bf16 shorts): xb 2359296; 7 weight/rel bufs x 589824;
// qb,kb,vtb 3x2359296; pkb,pqb 2x589824; valsb 2359296. ~34.2 MB.
// ---------------------------------------------------------------------------
extern "C" void kernel_launch(void* const* d_in, const int* in_sizes, int n_in,
                              void* d_out, int out_size, void* d_ws, size_t ws_size,
                              hipStream_t stream)
{
    const float* x         = (const float*)d_in[0];
    const int*   mask      = (const int*)d_in[1];
    const int*   seg       = (const int*)d_in[2];
    const float* sep       = (const float*)d_in[3];
    const float* Wq        = (const float*)d_in[4];
    const float* bq        = (const float*)d_in[5];
    const float* Wk        = (const float*)d_in[6];
    const float* bk        = (const float*)d_in[7];
    const float* Wv        = (const float*)d_in[8];
    const float* bv        = (const float*)d_in[9];
    const float* rel_emb   = (const float*)d_in[10];
    const float* Wpk       = (const float*)d_in[11];
    const float* bpk       = (const float*)d_in[12];
    const float* Wpq       = (const float*)d_in[13];
    const float* bpq       = (const float*)d_in[14];
    const float* same_bias = (const float*)d_in[15];
    const float* cross_bias= (const float*)d_in[16];
    const float* sep_scale = (const float*)d_in[17];
    const float* sep_decay = (const float*)d_in[18];
    const float* Wo        = (const float*)d_in[19];
    const float* bo        = (const float*)d_in[20];

    const size_t QKVN = (size_t)B_ * S_ * E_;   // 2359296
    const size_t WN   = (size_t)768 * 768;      //  589824

    unsigned short* xb    = (unsigned short*)d_ws;
    unsigned short* wqb   = xb   + QKVN;
    unsigned short* wkb   = wqb  + WN;
    unsigned short* wvb   = wkb  + WN;
    unsigned short* wob   = wvb  + WN;
    unsigned short* wpkb  = wob  + WN;
    unsigned short* wpqb  = wpkb + WN;
    unsigned short* relb  = wpqb + WN;
    unsigned short* qb    = relb + WN;
    unsigned short* kb    = qb   + QKVN;
    unsigned short* vtb   = kb   + QKVN;
    unsigned short* pkb   = vtb  + QKVN;
    unsigned short* pqb   = pkb  + WN;
    unsigned short* valsb = pqb  + WN;

    // 1) convert all operands to bf16
    convert_all<<<dim3(576, 11), 256, 0, stream>>>(
        x, Wq, Wk, Wv, Wo, Wpk, Wpq, rel_emb + (size_t)128 * D_,
        xb, wqb, wkb, wvb, wob, wpkb, wpqb, relb);

    // 2) fused Q/K/Vt/pk/pq projections
    proj_all<<<dim3(6, 24, 5), 256, 0, stream>>>(
        xb, relb, wqb, wkb, wvb, wpkb, wpqb,
        bq, bk, bv, bpk, bpq, qb, kb, vtb, pkb, pqb);

    // 3) MFMA flash attention v3
    attn_mfma<<<dim3(S_ / 64, H_, B_), 256, 0, stream>>>(
        qb, kb, vtb, pkb, pqb, seg, sep, mask,
        same_bias, cross_bias, sep_scale, sep_decay, valsb);

    // 4) output projection
    gemm_out<<<dim3(6, 24), 256, 0, stream>>>(valsb, wob, bo, (float*)d_out);
}

// Round 6
// 268.047 us; speedup vs baseline: 13.5638x; 1.0918x over previous
//
#include <hip/hip_runtime.h>
#include <math.h>

// Problem constants
#define B_  8
#define S_  384
#define H_  12
#define HD_ 64
#define E_  768
#define D_  768

typedef float  floatx4 __attribute__((ext_vector_type(4)));
typedef __bf16 bf16x8  __attribute__((ext_vector_type(8)));
typedef unsigned int ux4 __attribute__((ext_vector_type(4)));

__device__ __forceinline__ unsigned short f2bf(float f) {
    union { float f; unsigned u; } x; x.f = f;
    unsigned r = x.u + 0x7fff + ((x.u >> 16) & 1);
    return (unsigned short)(r >> 16);
}
__device__ __forceinline__ float bf2f(unsigned short u) {
    union { unsigned u; float f; } x; x.u = ((unsigned)u) << 16;
    return x.f;
}
__device__ __forceinline__ bf16x8 gld8(const unsigned short* p) {
    return __builtin_bit_cast(bf16x8, *(const ux4*)p);
}

// ---------------------------------------------------------------------------
// Fused fp32 -> bf16 convert. grid=(576,11).
// ---------------------------------------------------------------------------
__global__ __launch_bounds__(256) void convert_all(
    const float* __restrict__ x,
    const float* __restrict__ Wq, const float* __restrict__ Wk,
    const float* __restrict__ Wv, const float* __restrict__ Wo,
    const float* __restrict__ Wpk, const float* __restrict__ Wpq,
    const float* __restrict__ rel128,
    unsigned short* __restrict__ xb,
    unsigned short* __restrict__ wqb, unsigned short* __restrict__ wkb,
    unsigned short* __restrict__ wvb, unsigned short* __restrict__ wob,
    unsigned short* __restrict__ wpkb, unsigned short* __restrict__ wpqb,
    unsigned short* __restrict__ relb)
{
    const int seg = blockIdx.y;
    const int e = (blockIdx.x * 256 + threadIdx.x) * 4;
    const float* src;
    unsigned short* dst;
    if (seg < 4)       { src = x + (size_t)seg * 589824; dst = xb + (size_t)seg * 589824; }
    else if (seg == 4) { src = Wq;  dst = wqb; }
    else if (seg == 5) { src = Wk;  dst = wkb; }
    else if (seg == 6) { src = Wv;  dst = wvb; }
    else if (seg == 7) { src = Wo;  dst = wob; }
    else if (seg == 8) { src = Wpk; dst = wpkb; }
    else if (seg == 9) { src = Wpq; dst = wpqb; }
    else               { src = rel128; dst = relb; }

    float4 v;
    if (seg == 10 && e >= 767 * 768) v = make_float4(0.f, 0.f, 0.f, 0.f);
    else                             v = *(const float4*)(src + e);
    ushort4 o;
    o.x = f2bf(v.x); o.y = f2bf(v.y); o.z = f2bf(v.z); o.w = f2bf(v.w);
    *(ushort4*)(dst + e) = o;
}

// ---------------------------------------------------------------------------
// Fused projection GEMMs (Q,K,Vt,pk,pq) in one launch. grid=(6,24,5).
// ---------------------------------------------------------------------------
__global__ __launch_bounds__(256) void proj_all(
    const unsigned short* __restrict__ xb, const unsigned short* __restrict__ relb,
    const unsigned short* __restrict__ wq, const unsigned short* __restrict__ wk,
    const unsigned short* __restrict__ wv, const unsigned short* __restrict__ wpk,
    const unsigned short* __restrict__ wpq,
    const float* __restrict__ bq, const float* __restrict__ bk,
    const float* __restrict__ bv, const float* __restrict__ bpk,
    const float* __restrict__ bpq,
    unsigned short* __restrict__ qb, unsigned short* __restrict__ kb,
    unsigned short* __restrict__ vtb, unsigned short* __restrict__ pkb,
    unsigned short* __restrict__ pqb)
{
    const int z = blockIdx.z;
    if (z >= 3 && blockIdx.y >= 6) return;

    const unsigned short* A = (z < 3) ? xb : relb;
    const unsigned short* W = (z == 0) ? wq : (z == 1) ? wk : (z == 2) ? wv
                            : (z == 3) ? wpk : wpq;
    const float* bias = (z == 0) ? bq : (z == 1) ? bk : (z == 2) ? bv
                      : (z == 3) ? bpk : bpq;
    unsigned short* C = (z == 0) ? qb : (z == 1) ? kb : (z == 2) ? vtb
                      : (z == 3) ? pkb : pqb;

    __shared__ unsigned short As[128 * 32];
    __shared__ unsigned short Ws[128 * 32];

    const int tid  = threadIdx.x;
    const int lane = tid & 63;
    const int wv_  = tid >> 6;
    const int wy   = wv_ >> 1, wx = wv_ & 1;
    const int quad = lane >> 4, l16 = lane & 15;
    const int m0 = blockIdx.y * 128, n0 = blockIdx.x * 128;

    floatx4 acc[4][4];
#pragma unroll
    for (int i = 0; i < 4; ++i)
#pragma unroll
        for (int j = 0; j < 4; ++j) acc[i][j] = (floatx4){0.f, 0.f, 0.f, 0.f};

    const int koff = quad * 8;

    for (int k0 = 0; k0 < 768; k0 += 32) {
        __syncthreads();
#pragma unroll
        for (int r = 0; r < 2; ++r) {
            int idx = tid + 256 * r;
            int row = idx >> 2, c8 = (idx & 3) * 8;
            const unsigned short* ga = A + (size_t)(m0 + row) * 768 + k0 + c8;
            const unsigned short* gw = W + (size_t)(n0 + row) * 768 + k0 + c8;
            __builtin_amdgcn_global_load_lds(
                (__attribute__((address_space(1))) void*)ga,
                (__attribute__((address_space(3))) void*)&As[idx * 8], 16, 0, 0);
            __builtin_amdgcn_global_load_lds(
                (__attribute__((address_space(1))) void*)gw,
                (__attribute__((address_space(3))) void*)&Ws[idx * 8], 16, 0, 0);
        }
        __syncthreads();

        bf16x8 a[4], b[4];
#pragma unroll
        for (int mi = 0; mi < 4; ++mi)
            a[mi] = __builtin_bit_cast(bf16x8,
                *(const ux4*)&As[(wy * 64 + mi * 16 + l16) * 32 + koff]);
#pragma unroll
        for (int ni = 0; ni < 4; ++ni)
            b[ni] = __builtin_bit_cast(bf16x8,
                *(const ux4*)&Ws[(wx * 64 + ni * 16 + l16) * 32 + koff]);
#pragma unroll
        for (int mi = 0; mi < 4; ++mi)
#pragma unroll
            for (int ni = 0; ni < 4; ++ni)
                acc[mi][ni] = __builtin_amdgcn_mfma_f32_16x16x32_bf16(
                    a[mi], b[ni], acc[mi][ni], 0, 0, 0);
    }

#pragma unroll
    for (int ni = 0; ni < 4; ++ni) {
        const int n = n0 + wx * 64 + ni * 16 + l16;
        const float bn = bias[n];
#pragma unroll
        for (int mi = 0; mi < 4; ++mi) {
            const int mbase = m0 + wy * 64 + mi * 16 + quad * 4;
            if (z == 2) {
                const int bb = mbase / S_, s = mbase - bb * S_;
                const int h = n >> 6, hd = n & 63;
                ushort4 o;
                o.x = f2bf(acc[mi][ni][0] + bn);
                o.y = f2bf(acc[mi][ni][1] + bn);
                o.z = f2bf(acc[mi][ni][2] + bn);
                o.w = f2bf(acc[mi][ni][3] + bn);
                *(ushort4*)&C[(((size_t)(bb * H_ + h) << 6) + hd) * S_ + s] = o;
            } else if (z < 2) {
#pragma unroll
                for (int reg = 0; reg < 4; ++reg) {
                    const int m = mbase + reg;
                    const int bb = m / S_, s = m - bb * S_;
                    const int h = n >> 6, hd = n & 63;
                    C[(((size_t)(bb * H_ + h) * S_ + s) << 6) + hd] =
                        f2bf(acc[mi][ni][reg] + bn);
                }
            } else {
#pragma unroll
                for (int reg = 0; reg < 4; ++reg)
                    C[(size_t)(mbase + reg) * 768 + n] = f2bf(acc[mi][ni][reg] + bn);
            }
        }
    }
}

// ---------------------------------------------------------------------------
// Output projection: fp32 out = valsb(bf16) @ Wo^T + bo. grid=(6,24).
// ---------------------------------------------------------------------------
__global__ __launch_bounds__(256) void gemm_out(
    const unsigned short* __restrict__ A, const unsigned short* __restrict__ W,
    const float* __restrict__ bias, float* __restrict__ C)
{
    __shared__ unsigned short As[128 * 32];
    __shared__ unsigned short Ws[128 * 32];

    const int tid  = threadIdx.x;
    const int lane = tid & 63;
    const int wv_  = tid >> 6;
    const int wy   = wv_ >> 1, wx = wv_ & 1;
    const int quad = lane >> 4, l16 = lane & 15;
    const int m0 = blockIdx.y * 128, n0 = blockIdx.x * 128;

    floatx4 acc[4][4];
#pragma unroll
    for (int i = 0; i < 4; ++i)
#pragma unroll
        for (int j = 0; j < 4; ++j) acc[i][j] = (floatx4){0.f, 0.f, 0.f, 0.f};

    const int koff = quad * 8;

    for (int k0 = 0; k0 < 768; k0 += 32) {
        __syncthreads();
#pragma unroll
        for (int r = 0; r < 2; ++r) {
            int idx = tid + 256 * r;
            int row = idx >> 2, c8 = (idx & 3) * 8;
            const unsigned short* ga = A + (size_t)(m0 + row) * 768 + k0 + c8;
            const unsigned short* gw = W + (size_t)(n0 + row) * 768 + k0 + c8;
            __builtin_amdgcn_global_load_lds(
                (__attribute__((address_space(1))) void*)ga,
                (__attribute__((address_space(3))) void*)&As[idx * 8], 16, 0, 0);
            __builtin_amdgcn_global_load_lds(
                (__attribute__((address_space(1))) void*)gw,
                (__attribute__((address_space(3))) void*)&Ws[idx * 8], 16, 0, 0);
        }
        __syncthreads();

        bf16x8 a[4], b[4];
#pragma unroll
        for (int mi = 0; mi < 4; ++mi)
            a[mi] = __builtin_bit_cast(bf16x8,
                *(const ux4*)&As[(wy * 64 + mi * 16 + l16) * 32 + koff]);
#pragma unroll
        for (int ni = 0; ni < 4; ++ni)
            b[ni] = __builtin_bit_cast(bf16x8,
                *(const ux4*)&Ws[(wx * 64 + ni * 16 + l16) * 32 + koff]);
#pragma unroll
        for (int mi = 0; mi < 4; ++mi)
#pragma unroll
            for (int ni = 0; ni < 4; ++ni)
                acc[mi][ni] = __builtin_amdgcn_mfma_f32_16x16x32_bf16(
                    a[mi], b[ni], acc[mi][ni], 0, 0, 0);
    }

#pragma unroll
    for (int ni = 0; ni < 4; ++ni) {
        const int n = n0 + wx * 64 + ni * 16 + l16;
        const float bn = bias[n];
#pragma unroll
        for (int mi = 0; mi < 4; ++mi)
#pragma unroll
            for (int reg = 0; reg < 4; ++reg) {
                const int m = m0 + wy * 64 + mi * 16 + quad * 4 + reg;
                C[(size_t)m * 768 + n] = acc[mi][ni][reg] + bn;
            }
    }
}

// ---------------------------------------------------------------------------
// MFMA flash attention v4 — split-j for concurrency.
// grid = (6 it, 12 h, 24 = b*3+jc); block = 256 thr = 4 waves. Each block
// processes j-tiles {2jc, 2jc+1} and emits UNNORMALIZED partial O (bf16)
// plus per-row (m,l) fp32. merge_attn combines the 3 partials.
// Band-RMW structure (no atomics), 2 barriers/j-tile, no asm fences (LDS
// is in-order per wave; all fence-guarded hazards were same-wave).
// LDS ~29.5 KB -> 5 blocks/CU; __launch_bounds__(256,5) caps VGPR<=102.
// ---------------------------------------------------------------------------
__global__ __launch_bounds__(256, 5) void attn_mfma(
    const unsigned short* __restrict__ qg, const unsigned short* __restrict__ kg,
    const unsigned short* __restrict__ vtg,
    const unsigned short* __restrict__ pkg, const unsigned short* __restrict__ pqg,
    const int* __restrict__ seg, const float* __restrict__ sep,
    const int* __restrict__ mask,
    const float* __restrict__ same_bias, const float* __restrict__ cross_bias,
    const float* __restrict__ sep_scale, const float* __restrict__ sep_decay,
    unsigned short* __restrict__ part_O, float* __restrict__ part_ml)
{
    __shared__ float CP[64 * 68];              // fp32 score tile, pitch 68
    __shared__ unsigned short Pp[64 * 72];     // bf16 P, pitch 72
    __shared__ float alpha_s[64], m_s[64], l_s[64], ai_s[64];
    __shared__ int   si_s[64];
    __shared__ float aj_s[2][64];
    __shared__ int   sj_s[2][64], mj_s[2][64];

    const int tid  = threadIdx.x;
    const int lane = tid & 63, w = tid >> 6;
    const int l16  = lane & 15, quad = lane >> 4;
    const int ty = tid >> 4, tx = tid & 15;
    const int it = blockIdx.x, h = blockIdx.y;
    const int b  = blockIdx.z / 3, jc = blockIdx.z - 3 * b;
    const int i0 = it * 64;
    const size_t bh = (size_t)(b * H_ + h);

    const unsigned short* kbase  = kg  + bh * S_ * 64;
    const unsigned short* vtbase = vtg + bh * 64 * S_;

    // Q A-fragments in registers (strip w)
    bf16x8 qf[2];
#pragma unroll
    for (int ks = 0; ks < 2; ++ks)
        qf[ks] = gld8(qg + (bh * S_ + i0 + 16 * w + l16) * 64 + ks * 32 + quad * 8);

    if (lane < 16) {
        const int ii = 16 * w + lane;
        m_s[ii] = -INFINITY; l_s[ii] = 0.f;
        ai_s[ii] = fabsf(sep[b * S_ + i0 + ii]);
        si_s[ii] = seg[b * S_ + i0 + ii];
    }

    const float sb  = same_bias[h];
    const float cb  = cross_bias[h];
    const float ssc = sep_scale[h];
    const float sd  = sep_decay[h];
    const float dec = fmaxf(sd, 0.f) + log1pf(__expf(-fabsf(sd))) + 1e-4f;
    const float isc = 0.07216878364870323f;   // 1/sqrt(64*3)

    floatx4 O[4];
#pragma unroll
    for (int nd = 0; nd < 4; ++nd) O[nd] = (floatx4){0.f, 0.f, 0.f, 0.f};

#pragma unroll
    for (int t = 0; t < 2; ++t) {
        const int jt = 2 * jc + t;
        const int j0 = jt * 64;
        const int pr = t;                    // parity buffer
        const int dbase = i0 - j0 + 320;     // pk/pq window base (0..640)

        if (lane < 16) {
            const int jj = 16 * w + lane;
            aj_s[pr][jj] = fabsf(sep[b * S_ + j0 + jj]);
            sj_s[pr][jj] = seg[b * S_ + j0 + jj];
            mj_s[pr][jj] = mask[b * S_ + j0 + jj];
        }

        // ---- phase A (wave-private rows strip w): c2c store + c2p RMW ----
#pragma unroll
        for (int nj = 0; nj < 4; ++nj) {
            floatx4 acc = (floatx4){0.f, 0.f, 0.f, 0.f};
#pragma unroll
            for (int ks = 0; ks < 2; ++ks) {
                bf16x8 bf = gld8(kbase + (size_t)(j0 + 16 * nj + l16) * 64 + ks * 32 + quad * 8);
                acc = __builtin_amdgcn_mfma_f32_16x16x32_bf16(qf[ks], bf, acc, 0, 0, 0);
            }
#pragma unroll
            for (int reg = 0; reg < 4; ++reg) {
                const int ii = 16 * w + quad * 4 + reg;
                CP[ii * 68 + 16 * nj + l16] = acc[reg];
            }
        }
#pragma unroll
        for (int f = 0; f < 5; ++f) {
            const int nd = w + f;
            floatx4 acc = (floatx4){0.f, 0.f, 0.f, 0.f};
#pragma unroll
            for (int ks = 0; ks < 2; ++ks) {
                bf16x8 bf = gld8(pkg + (size_t)(dbase + 16 * nd + l16) * 768 + h * 64 + ks * 32 + quad * 8);
                acc = __builtin_amdgcn_mfma_f32_16x16x32_bf16(qf[ks], bf, acc, 0, 0, 0);
            }
            const int ddloc = 16 * nd + l16;
#pragma unroll
            for (int reg = 0; reg < 4; ++reg) {
                const int ii = 16 * w + quad * 4 + reg;
                const int jj = ii - ddloc + 63;
                if (jj >= 0 && jj < 64)
                    CP[ii * 68 + jj] += acc[reg];     // unique writer per cell
            }
        }
        __syncthreads();   // B1: rows complete -> column-band phase

        // ---- p2c (cols strip w): A = K rows strip w, banded RMW ----
        bf16x8 kfA[2];
#pragma unroll
        for (int ks = 0; ks < 2; ++ks)
            kfA[ks] = gld8(kbase + (size_t)(j0 + 16 * w + l16) * 64 + ks * 32 + quad * 8);
#pragma unroll
        for (int f = 0; f < 5; ++f) {
            const int nd = 3 - w + f;
            floatx4 acc = (floatx4){0.f, 0.f, 0.f, 0.f};
#pragma unroll
            for (int ks = 0; ks < 2; ++ks) {
                bf16x8 bf = gld8(pqg + (size_t)(dbase + 16 * nd + l16) * 768 + h * 64 + ks * 32 + quad * 8);
                acc = __builtin_amdgcn_mfma_f32_16x16x32_bf16(kfA[ks], bf, acc, 0, 0, 0);
            }
            const int ddloc = 16 * nd + l16;
#pragma unroll
            for (int reg = 0; reg < 4; ++reg) {
                const int jj = 16 * w + quad * 4 + reg;
                const int ii = ddloc + jj - 63;
                if (ii >= 0 && ii < 64)
                    CP[ii * 68 + jj] += acc[reg];     // unique writer per cell
            }
        }
        __syncthreads();   // B2: full score tile ready

        // ---- softmax (wave-private rows strip w) ----
#pragma unroll
        for (int p = 0; p < 4; ++p) {
            const int ii = 4 * ty + p;
            const float aii = ai_s[ii];
            const int   sii = si_s[ii];
            float lg[4];
            float tmax = -INFINITY;
#pragma unroll
            for (int r = 0; r < 4; ++r) {
                const int jl = 4 * tx + r;
                float xv = CP[ii * 68 + jl] * isc;
                const float gap = fabsf(aii - aj_s[pr][jl]);
                const float bias = (sii == sj_s[pr][jl]) ? sb
                                 : cb + __expf(-gap * dec) * ssc;
                xv += bias;
                if (mj_s[pr][jl] == 0) xv = -9.0e15f;
                lg[r] = xv;
                tmax = fmaxf(tmax, xv);
            }
#pragma unroll
            for (int off = 1; off < 16; off <<= 1)
                tmax = fmaxf(tmax, __shfl_xor(tmax, off));
            const float mp = m_s[ii];
            const float nm = fmaxf(mp, tmax);
            const float alpha = __expf(mp - nm);
            float rs = 0.f;
            ushort4 pw;
#pragma unroll
            for (int r = 0; r < 4; ++r) {
                const float e = __expf(lg[r] - nm);
                rs += e;
                ((unsigned short*)&pw)[r] = f2bf(e);
            }
#pragma unroll
            for (int off = 1; off < 16; off <<= 1)
                rs += __shfl_xor(rs, off);
            if (tx == 0) {
                m_s[ii] = nm;
                alpha_s[ii] = alpha;
                l_s[ii] = l_s[ii] * alpha + rs;
            }
            *(ushort4*)&Pp[ii * 72 + 4 * tx] = pw;
        }

        // ---- PV (wave-private): O += P(strip w) x Vt ----
        float av[4];
#pragma unroll
        for (int reg = 0; reg < 4; ++reg)
            av[reg] = alpha_s[16 * w + quad * 4 + reg];
        bf16x8 pA[2];
#pragma unroll
        for (int ks = 0; ks < 2; ++ks)
            pA[ks] = __builtin_bit_cast(bf16x8,
                *(const ux4*)&Pp[(16 * w + l16) * 72 + ks * 32 + quad * 8]);
#pragma unroll
        for (int nd = 0; nd < 4; ++nd) {
#pragma unroll
            for (int reg = 0; reg < 4; ++reg) O[nd][reg] *= av[reg];
#pragma unroll
            for (int ks = 0; ks < 2; ++ks) {
                bf16x8 bf = gld8(vtbase + (size_t)(16 * nd + l16) * S_ + j0 + ks * 32 + quad * 8);
                O[nd] = __builtin_amdgcn_mfma_f32_16x16x32_bf16(pA[ks], bf, O[nd], 0, 0, 0);
            }
        }
        // no barrier: next tile's phase A touches only wave-private rows
    }

    // ---- epilogue: write UNNORMALIZED partial O + (m,l) ----
    const int idx = ((b * H_ + h) * 6 + it);          // 0..575
    unsigned short* pO = part_O + ((size_t)(jc * 576 + idx)) * 4096;
    float* pml = part_ml + (size_t)(jc * 576 + idx) * 128;
#pragma unroll
    for (int nd = 0; nd < 4; ++nd) {
        const int d = 16 * nd + l16;
#pragma unroll
        for (int reg = 0; reg < 4; ++reg) {
            const int ii = 16 * w + quad * 4 + reg;
            pO[ii * 64 + d] = f2bf(O[nd][reg]);
        }
    }
    if (lane < 16) {
        const int ii = 16 * w + lane;
        pml[ii]      = m_s[ii];
        pml[64 + ii] = l_s[ii];
    }
}

// ---------------------------------------------------------------------------
// Merge the 3 split-j partials -> vals (bf16, (B,S,E)).
// grid = 576 blocks, 256 thr; thread handles (row ii = tid/4, 16 d's).
// ---------------------------------------------------------------------------
__global__ __launch_bounds__(256) void merge_attn(
    const unsigned short* __restrict__ part_O, const float* __restrict__ part_ml,
    unsigned short* __restrict__ vals)
{
    const int idx = blockIdx.x;                 // ((b*H+h)*6+it)
    const int b  = idx / (H_ * 6);
    const int r  = idx - b * H_ * 6;
    const int h  = r / 6, it = r - h * 6;
    const int tid = threadIdx.x;
    const int ii = tid >> 2, c = (tid & 3) * 16;

    float m[3], l[3];
#pragma unroll
    for (int jc = 0; jc < 3; ++jc) {
        const float* pml = part_ml + (size_t)(jc * 576 + idx) * 128;
        m[jc] = pml[ii];
        l[jc] = pml[64 + ii];
    }
    float M = fmaxf(fmaxf(m[0], m[1]), m[2]);
    float wsum = 0.f, wc[3];
#pragma unroll
    for (int jc = 0; jc < 3; ++jc) {
        wc[jc] = __expf(m[jc] - M);
        wsum += wc[jc] * l[jc];
    }
    const float inv = (wsum > 0.f) ? 1.f / wsum : 0.f;

    float o[16];
#pragma unroll
    for (int e = 0; e < 16; ++e) o[e] = 0.f;
#pragma unroll
    for (int jc = 0; jc < 3; ++jc) {
        const unsigned short* pO = part_O + ((size_t)(jc * 576 + idx)) * 4096
                                 + ii * 64 + c;
        ux4 u0 = *(const ux4*)pO;
        ux4 u1 = *(const ux4*)(pO + 8);
        const unsigned short* us0 = (const unsigned short*)&u0;
        const unsigned short* us1 = (const unsigned short*)&u1;
#pragma unroll
        for (int e = 0; e < 8; ++e) {
            o[e]     += wc[jc] * bf2f(us0[e]);
            o[8 + e] += wc[jc] * bf2f(us1[e]);
        }
    }
    ushort4 w0, w1, w2, w3;
#pragma unroll
    for (int e = 0; e < 4; ++e) {
        ((unsigned short*)&w0)[e] = f2bf(o[e] * inv);
        ((unsigned short*)&w1)[e] = f2bf(o[4 + e] * inv);
        ((unsigned short*)&w2)[e] = f2bf(o[8 + e] * inv);
        ((unsigned short*)&w3)[e] = f2bf(o[12 + e] * inv);
    }
    unsigned short* dst = vals + ((size_t)(b * S_ + it * 64 + ii)) * E_ + h * 64 + c;
    *(ushort4*)(dst)      = w0;
    *(ushort4*)(dst + 4)  = w1;
    *(ushort4*)(dst + 8)  = w2;
    *(ushort4*)(dst + 12) = w3;
}

// ---------------------------------------------------------------------------
// Launcher. Workspace (shorts unless noted): xb 2359296; 7x589824 weights/rel;
// qb,kb,vtb 3x2359296; pkb,pqb 2x589824; valsb 2359296; part_O 3x576x4096;
// part_ml fp32 3x576x128. Total ~49.3 MB.
// ---------------------------------------------------------------------------
extern "C" void kernel_launch(void* const* d_in, const int* in_sizes, int n_in,
                              void* d_out, int out_size, void* d_ws, size_t ws_size,
                              hipStream_t stream)
{
    const float* x         = (const float*)d_in[0];
    const int*   mask      = (const int*)d_in[1];
    const int*   seg       = (const int*)d_in[2];
    const float* sep       = (const float*)d_in[3];
    const float* Wq        = (const float*)d_in[4];
    const float* bq        = (const float*)d_in[5];
    const float* Wk        = (const float*)d_in[6];
    const float* bk        = (const float*)d_in[7];
    const float* Wv        = (const float*)d_in[8];
    const float* bv        = (const float*)d_in[9];
    const float* rel_emb   = (const float*)d_in[10];
    const float* Wpk       = (const float*)d_in[11];
    const float* bpk       = (const float*)d_in[12];
    const float* Wpq       = (const float*)d_in[13];
    const float* bpq       = (const float*)d_in[14];
    const float* same_bias = (const float*)d_in[15];
    const float* cross_bias= (const float*)d_in[16];
    const float* sep_scale = (const float*)d_in[17];
    const float* sep_decay = (const float*)d_in[18];
    const float* Wo        = (const float*)d_in[19];
    const float* bo        = (const float*)d_in[20];

    const size_t QKVN = (size_t)B_ * S_ * E_;   // 2359296
    const size_t WN   = (size_t)768 * 768;      //  589824

    unsigned short* xb    = (unsigned short*)d_ws;
    unsigned short* wqb   = xb   + QKVN;
    unsigned short* wkb   = wqb  + WN;
    unsigned short* wvb   = wkb  + WN;
    unsigned short* wob   = wvb  + WN;
    unsigned short* wpkb  = wob  + WN;
    unsigned short* wpqb  = wpkb + WN;
    unsigned short* relb  = wpqb + WN;
    unsigned short* qb    = relb + WN;
    unsigned short* kb    = qb   + QKVN;
    unsigned short* vtb   = kb   + QKVN;
    unsigned short* pkb   = vtb  + QKVN;
    unsigned short* pqb   = pkb  + WN;
    unsigned short* valsb = pqb  + WN;
    unsigned short* partO = valsb + QKVN;                       // 3*576*4096 shorts
    float*          partml= (float*)(partO + (size_t)3 * 576 * 4096);

    // 1) convert all operands to bf16
    convert_all<<<dim3(576, 11), 256, 0, stream>>>(
        x, Wq, Wk, Wv, Wo, Wpk, Wpq, rel_emb + (size_t)128 * D_,
        xb, wqb, wkb, wvb, wob, wpkb, wpqb, relb);

    // 2) fused Q/K/Vt/pk/pq projections
    proj_all<<<dim3(6, 24, 5), 256, 0, stream>>>(
        xb, relb, wqb, wkb, wvb, wpkb, wpqb,
        bq, bk, bv, bpk, bpq, qb, kb, vtb, pkb, pqb);

    // 3) MFMA flash attention, split-j x3
    attn_mfma<<<dim3(6, 12, 24), 256, 0, stream>>>(
        qb, kb, vtb, pkb, pqb, seg, sep, mask,
        same_bias, cross_bias, sep_scale, sep_decay, partO, partml);

    // 4) merge partials -> valsb
    merge_attn<<<dim3(576), 256, 0, stream>>>(partO, partml, valsb);

    // 5) output projection
    gemm_out<<<dim3(6, 24), 256, 0, stream>>>(valsb, wob, bo, (float*)d_out);
}

// Round 7
// 249.875 us; speedup vs baseline: 14.5503x; 1.0727x over previous
//
#include <hip/hip_runtime.h>
#include <math.h>

// Problem constants
#define B_  8
#define S_  384
#define H_  12
#define HD_ 64
#define E_  768
#define D_  768

typedef float  floatx4 __attribute__((ext_vector_type(4)));
typedef __bf16 bf16x8  __attribute__((ext_vector_type(8)));
typedef unsigned int ux4 __attribute__((ext_vector_type(4)));

__device__ __forceinline__ unsigned short f2bf(float f) {
    union { float f; unsigned u; } x; x.f = f;
    unsigned r = x.u + 0x7fff + ((x.u >> 16) & 1);
    return (unsigned short)(r >> 16);
}
__device__ __forceinline__ float bf2f(unsigned short u) {
    union { unsigned u; float f; } x; x.u = ((unsigned)u) << 16;
    return x.f;
}
__device__ __forceinline__ bf16x8 gld8(const unsigned short* p) {
    return __builtin_bit_cast(bf16x8, *(const ux4*)p);
}

// ---------------------------------------------------------------------------
// Fused fp32 -> bf16 convert. grid=(576,11).
// ---------------------------------------------------------------------------
__global__ __launch_bounds__(256) void convert_all(
    const float* __restrict__ x,
    const float* __restrict__ Wq, const float* __restrict__ Wk,
    const float* __restrict__ Wv, const float* __restrict__ Wo,
    const float* __restrict__ Wpk, const float* __restrict__ Wpq,
    const float* __restrict__ rel128,
    unsigned short* __restrict__ xb,
    unsigned short* __restrict__ wqb, unsigned short* __restrict__ wkb,
    unsigned short* __restrict__ wvb, unsigned short* __restrict__ wob,
    unsigned short* __restrict__ wpkb, unsigned short* __restrict__ wpqb,
    unsigned short* __restrict__ relb)
{
    const int seg = blockIdx.y;
    const int e = (blockIdx.x * 256 + threadIdx.x) * 4;
    const float* src;
    unsigned short* dst;
    if (seg < 4)       { src = x + (size_t)seg * 589824; dst = xb + (size_t)seg * 589824; }
    else if (seg == 4) { src = Wq;  dst = wqb; }
    else if (seg == 5) { src = Wk;  dst = wkb; }
    else if (seg == 6) { src = Wv;  dst = wvb; }
    else if (seg == 7) { src = Wo;  dst = wob; }
    else if (seg == 8) { src = Wpk; dst = wpkb; }
    else if (seg == 9) { src = Wpq; dst = wpqb; }
    else               { src = rel128; dst = relb; }

    float4 v;
    if (seg == 10 && e >= 767 * 768) v = make_float4(0.f, 0.f, 0.f, 0.f);
    else                             v = *(const float4*)(src + e);
    ushort4 o;
    o.x = f2bf(v.x); o.y = f2bf(v.y); o.z = f2bf(v.z); o.w = f2bf(v.w);
    *(ushort4*)(dst + e) = o;
}

// ---------------------------------------------------------------------------
// Fused projection GEMMs (Q,K,Vt,pk,pq) in one launch. grid=(6,24,5).
// ---------------------------------------------------------------------------
__global__ __launch_bounds__(256) void proj_all(
    const unsigned short* __restrict__ xb, const unsigned short* __restrict__ relb,
    const unsigned short* __restrict__ wq, const unsigned short* __restrict__ wk,
    const unsigned short* __restrict__ wv, const unsigned short* __restrict__ wpk,
    const unsigned short* __restrict__ wpq,
    const float* __restrict__ bq, const float* __restrict__ bk,
    const float* __restrict__ bv, const float* __restrict__ bpk,
    const float* __restrict__ bpq,
    unsigned short* __restrict__ qb, unsigned short* __restrict__ kb,
    unsigned short* __restrict__ vtb, unsigned short* __restrict__ pkb,
    unsigned short* __restrict__ pqb)
{
    const int z = blockIdx.z;
    if (z >= 3 && blockIdx.y >= 6) return;

    const unsigned short* A = (z < 3) ? xb : relb;
    const unsigned short* W = (z == 0) ? wq : (z == 1) ? wk : (z == 2) ? wv
                            : (z == 3) ? wpk : wpq;
    const float* bias = (z == 0) ? bq : (z == 1) ? bk : (z == 2) ? bv
                      : (z == 3) ? bpk : bpq;
    unsigned short* C = (z == 0) ? qb : (z == 1) ? kb : (z == 2) ? vtb
                      : (z == 3) ? pkb : pqb;

    __shared__ unsigned short As[128 * 32];
    __shared__ unsigned short Ws[128 * 32];

    const int tid  = threadIdx.x;
    const int lane = tid & 63;
    const int wv_  = tid >> 6;
    const int wy   = wv_ >> 1, wx = wv_ & 1;
    const int quad = lane >> 4, l16 = lane & 15;
    const int m0 = blockIdx.y * 128, n0 = blockIdx.x * 128;

    floatx4 acc[4][4];
#pragma unroll
    for (int i = 0; i < 4; ++i)
#pragma unroll
        for (int j = 0; j < 4; ++j) acc[i][j] = (floatx4){0.f, 0.f, 0.f, 0.f};

    const int koff = quad * 8;

    for (int k0 = 0; k0 < 768; k0 += 32) {
        __syncthreads();
#pragma unroll
        for (int r = 0; r < 2; ++r) {
            int idx = tid + 256 * r;
            int row = idx >> 2, c8 = (idx & 3) * 8;
            const unsigned short* ga = A + (size_t)(m0 + row) * 768 + k0 + c8;
            const unsigned short* gw = W + (size_t)(n0 + row) * 768 + k0 + c8;
            __builtin_amdgcn_global_load_lds(
                (__attribute__((address_space(1))) void*)ga,
                (__attribute__((address_space(3))) void*)&As[idx * 8], 16, 0, 0);
            __builtin_amdgcn_global_load_lds(
                (__attribute__((address_space(1))) void*)gw,
                (__attribute__((address_space(3))) void*)&Ws[idx * 8], 16, 0, 0);
        }
        __syncthreads();

        bf16x8 a[4], b[4];
#pragma unroll
        for (int mi = 0; mi < 4; ++mi)
            a[mi] = __builtin_bit_cast(bf16x8,
                *(const ux4*)&As[(wy * 64 + mi * 16 + l16) * 32 + koff]);
#pragma unroll
        for (int ni = 0; ni < 4; ++ni)
            b[ni] = __builtin_bit_cast(bf16x8,
                *(const ux4*)&Ws[(wx * 64 + ni * 16 + l16) * 32 + koff]);
#pragma unroll
        for (int mi = 0; mi < 4; ++mi)
#pragma unroll
            for (int ni = 0; ni < 4; ++ni)
                acc[mi][ni] = __builtin_amdgcn_mfma_f32_16x16x32_bf16(
                    a[mi], b[ni], acc[mi][ni], 0, 0, 0);
    }

#pragma unroll
    for (int ni = 0; ni < 4; ++ni) {
        const int n = n0 + wx * 64 + ni * 16 + l16;
        const float bn = bias[n];
#pragma unroll
        for (int mi = 0; mi < 4; ++mi) {
            const int mbase = m0 + wy * 64 + mi * 16 + quad * 4;
            if (z == 2) {
                const int bb = mbase / S_, s = mbase - bb * S_;
                const int h = n >> 6, hd = n & 63;
                ushort4 o;
                o.x = f2bf(acc[mi][ni][0] + bn);
                o.y = f2bf(acc[mi][ni][1] + bn);
                o.z = f2bf(acc[mi][ni][2] + bn);
                o.w = f2bf(acc[mi][ni][3] + bn);
                *(ushort4*)&C[(((size_t)(bb * H_ + h) << 6) + hd) * S_ + s] = o;
            } else if (z < 2) {
#pragma unroll
                for (int reg = 0; reg < 4; ++reg) {
                    const int m = mbase + reg;
                    const int bb = m / S_, s = m - bb * S_;
                    const int h = n >> 6, hd = n & 63;
                    C[(((size_t)(bb * H_ + h) * S_ + s) << 6) + hd] =
                        f2bf(acc[mi][ni][reg] + bn);
                }
            } else {
#pragma unroll
                for (int reg = 0; reg < 4; ++reg)
                    C[(size_t)(mbase + reg) * 768 + n] = f2bf(acc[mi][ni][reg] + bn);
            }
        }
    }
}

// ---------------------------------------------------------------------------
// Output projection: fp32 out = valsb(bf16) @ Wo^T + bo. grid=(6,24).
// ---------------------------------------------------------------------------
__global__ __launch_bounds__(256) void gemm_out(
    const unsigned short* __restrict__ A, const unsigned short* __restrict__ W,
    const float* __restrict__ bias, float* __restrict__ C)
{
    __shared__ unsigned short As[128 * 32];
    __shared__ unsigned short Ws[128 * 32];

    const int tid  = threadIdx.x;
    const int lane = tid & 63;
    const int wv_  = tid >> 6;
    const int wy   = wv_ >> 1, wx = wv_ & 1;
    const int quad = lane >> 4, l16 = lane & 15;
    const int m0 = blockIdx.y * 128, n0 = blockIdx.x * 128;

    floatx4 acc[4][4];
#pragma unroll
    for (int i = 0; i < 4; ++i)
#pragma unroll
        for (int j = 0; j < 4; ++j) acc[i][j] = (floatx4){0.f, 0.f, 0.f, 0.f};

    const int koff = quad * 8;

    for (int k0 = 0; k0 < 768; k0 += 32) {
        __syncthreads();
#pragma unroll
        for (int r = 0; r < 2; ++r) {
            int idx = tid + 256 * r;
            int row = idx >> 2, c8 = (idx & 3) * 8;
            const unsigned short* ga = A + (size_t)(m0 + row) * 768 + k0 + c8;
            const unsigned short* gw = W + (size_t)(n0 + row) * 768 + k0 + c8;
            __builtin_amdgcn_global_load_lds(
                (__attribute__((address_space(1))) void*)ga,
                (__attribute__((address_space(3))) void*)&As[idx * 8], 16, 0, 0);
            __builtin_amdgcn_global_load_lds(
                (__attribute__((address_space(1))) void*)gw,
                (__attribute__((address_space(3))) void*)&Ws[idx * 8], 16, 0, 0);
        }
        __syncthreads();

        bf16x8 a[4], b[4];
#pragma unroll
        for (int mi = 0; mi < 4; ++mi)
            a[mi] = __builtin_bit_cast(bf16x8,
                *(const ux4*)&As[(wy * 64 + mi * 16 + l16) * 32 + koff]);
#pragma unroll
        for (int ni = 0; ni < 4; ++ni)
            b[ni] = __builtin_bit_cast(bf16x8,
                *(const ux4*)&Ws[(wx * 64 + ni * 16 + l16) * 32 + koff]);
#pragma unroll
        for (int mi = 0; mi < 4; ++mi)
#pragma unroll
            for (int ni = 0; ni < 4; ++ni)
                acc[mi][ni] = __builtin_amdgcn_mfma_f32_16x16x32_bf16(
                    a[mi], b[ni], acc[mi][ni], 0, 0, 0);
    }

#pragma unroll
    for (int ni = 0; ni < 4; ++ni) {
        const int n = n0 + wx * 64 + ni * 16 + l16;
        const float bn = bias[n];
#pragma unroll
        for (int mi = 0; mi < 4; ++mi)
#pragma unroll
            for (int reg = 0; reg < 4; ++reg) {
                const int m = m0 + wy * 64 + mi * 16 + quad * 4 + reg;
                C[(size_t)m * 768 + n] = acc[mi][ni][reg] + bn;
            }
    }
}

// ---------------------------------------------------------------------------
// MFMA flash attention v5 — BARRIER-FREE j-loop.
// grid = (6 it, 12 h, 24 = b*3+jc); block = 256 thr = 4 waves; wave w owns
// row strip ii in [16w,16w+16) end-to-end. Per j-tile:
//   c2c : Q(reg) x K        -> CP rows strip w (store)
//   c2p : Q(reg) x PK frags nd=w..w+4, scatter jj=ii-ddloc+63  (row-banded)
//   p2c : PQ(m=ddloc) x K(n=jj), frags with nd+nj in {w+3,w+4} (row-banded:
//         output ii = ddloc+jj-63; guard ii in strip w; unique writer/cell)
//   softmax rows strip w (bias/mask/online-m,l); P -> Pp strip w (bf16)
//   PV  : P(strip w) x Vt -> O regs
// ALL LDS traffic is wave-private (same-wave DS is in-order + compiler
// may-alias waits) => ZERO __syncthreads; waves fully decoupled.
// K B-frags shared between c2c and p2c (kept in regs). i/j metadata read
// directly from global (L1 broadcast). Emits unnormalized partial O + (m,l).
// LDS ~27.4 KB; __launch_bounds__(256,4).
// ---------------------------------------------------------------------------
__global__ __launch_bounds__(256, 4) void attn_mfma(
    const unsigned short* __restrict__ qg, const unsigned short* __restrict__ kg,
    const unsigned short* __restrict__ vtg,
    const unsigned short* __restrict__ pkg, const unsigned short* __restrict__ pqg,
    const int* __restrict__ seg, const float* __restrict__ sep,
    const int* __restrict__ mask,
    const float* __restrict__ same_bias, const float* __restrict__ cross_bias,
    const float* __restrict__ sep_scale, const float* __restrict__ sep_decay,
    unsigned short* __restrict__ part_O, float* __restrict__ part_ml)
{
    __shared__ float CP[64 * 68];              // fp32 score tile, pitch 68
    __shared__ unsigned short Pp[64 * 72];     // bf16 P, pitch 72
    __shared__ float alpha_s[64], m_s[64], l_s[64];

    const int tid  = threadIdx.x;
    const int lane = tid & 63, w = tid >> 6;
    const int l16  = lane & 15, quad = lane >> 4;
    const int ty = tid >> 4, tx = tid & 15;
    const int it = blockIdx.x, h = blockIdx.y;
    const int b  = blockIdx.z / 3, jc = blockIdx.z - 3 * b;
    const int i0 = it * 64;
    const size_t bh = (size_t)(b * H_ + h);

    const unsigned short* kbase  = kg  + bh * S_ * 64;
    const unsigned short* vtbase = vtg + bh * 64 * S_;

    // Q A-fragments in registers (strip w)
    bf16x8 qf[2];
#pragma unroll
    for (int ks = 0; ks < 2; ++ks)
        qf[ks] = gld8(qg + (bh * S_ + i0 + 16 * w + l16) * 64 + ks * 32 + quad * 8);

    // i-side metadata per softmax thread (rows 4ty..4ty+3), loaded once
    float ai_r[4]; int si_r[4];
#pragma unroll
    for (int p = 0; p < 4; ++p) {
        const int ii = 4 * ty + p;
        ai_r[p] = fabsf(sep[b * S_ + i0 + ii]);
        si_r[p] = seg[b * S_ + i0 + ii];
    }
    if (lane < 16) {
        const int ii = 16 * w + lane;
        m_s[ii] = -INFINITY; l_s[ii] = 0.f;
    }

    const float sb  = same_bias[h];
    const float cb  = cross_bias[h];
    const float ssc = sep_scale[h];
    const float sd  = sep_decay[h];
    const float dec = fmaxf(sd, 0.f) + log1pf(__expf(-fabsf(sd))) + 1e-4f;
    const float isc = 0.07216878364870323f;   // 1/sqrt(64*3)

    floatx4 O[4];
#pragma unroll
    for (int nd = 0; nd < 4; ++nd) O[nd] = (floatx4){0.f, 0.f, 0.f, 0.f};

#pragma unroll
    for (int t = 0; t < 2; ++t) {
        const int jt = 2 * jc + t;
        const int j0 = jt * 64;
        const int dbase = i0 - j0 + 320;     // pk/pq window base (0..640)

        // ---- K B-fragments (shared by c2c and p2c) ----
        bf16x8 kf[4][2];
#pragma unroll
        for (int nj = 0; nj < 4; ++nj)
#pragma unroll
            for (int ks = 0; ks < 2; ++ks)
                kf[nj][ks] = gld8(kbase + (size_t)(j0 + 16 * nj + l16) * 64 + ks * 32 + quad * 8);

        // ---- c2c: CP rows strip w = q . k ----
#pragma unroll
        for (int nj = 0; nj < 4; ++nj) {
            floatx4 acc = (floatx4){0.f, 0.f, 0.f, 0.f};
#pragma unroll
            for (int ks = 0; ks < 2; ++ks)
                acc = __builtin_amdgcn_mfma_f32_16x16x32_bf16(qf[ks], kf[nj][ks], acc, 0, 0, 0);
#pragma unroll
            for (int reg = 0; reg < 4; ++reg) {
                const int ii = 16 * w + quad * 4 + reg;
                CP[ii * 68 + 16 * nj + l16] = acc[reg];
            }
        }

        // ---- c2p (rows strip w): frags nd = w..w+4, scatter jj=ii-ddloc+63 ----
#pragma unroll
        for (int f = 0; f < 5; ++f) {
            const int nd = w + f;
            floatx4 acc = (floatx4){0.f, 0.f, 0.f, 0.f};
#pragma unroll
            for (int ks = 0; ks < 2; ++ks) {
                bf16x8 bf = gld8(pkg + (size_t)(dbase + 16 * nd + l16) * 768 + h * 64 + ks * 32 + quad * 8);
                acc = __builtin_amdgcn_mfma_f32_16x16x32_bf16(qf[ks], bf, acc, 0, 0, 0);
            }
            const int ddloc = 16 * nd + l16;
#pragma unroll
            for (int reg = 0; reg < 4; ++reg) {
                const int ii = 16 * w + quad * 4 + reg;
                const int jj = ii - ddloc + 63;
                if (jj >= 0 && jj < 64)
                    CP[ii * 68 + jj] += acc[reg];     // unique writer per cell
            }
        }

        // ---- p2c (rows strip w): A=PQ rows (m=ddloc), B=K (n=jj);
        //      frags with nd+nj in {w+3, w+4}; guard ii in strip w ----
#pragma unroll
        for (int f = 0; f < 5; ++f) {
            const int nd = w + f;
            bf16x8 pqf[2];
#pragma unroll
            for (int ks = 0; ks < 2; ++ks)
                pqf[ks] = gld8(pqg + (size_t)(dbase + 16 * nd + l16) * 768 + h * 64 + ks * 32 + quad * 8);
#pragma unroll
            for (int g = 0; g < 2; ++g) {
                const int nj = (g == 0) ? (3 - f) : (4 - f);
                if (nj < 0 || nj > 3) continue;
                floatx4 acc = (floatx4){0.f, 0.f, 0.f, 0.f};
#pragma unroll
                for (int ks = 0; ks < 2; ++ks)
                    acc = __builtin_amdgcn_mfma_f32_16x16x32_bf16(pqf[ks], kf[nj][ks], acc, 0, 0, 0);
                const int jj = 16 * nj + l16;
#pragma unroll
                for (int reg = 0; reg < 4; ++reg) {
                    const int ddloc = 16 * nd + quad * 4 + reg;
                    const int ii = ddloc + jj - 63;
                    if (ii >= 16 * w && ii < 16 * w + 16)
                        CP[ii * 68 + jj] += acc[reg]; // unique writer per cell
                }
            }
        }

        // ---- softmax (rows strip w; thread ty covers rows 4ty..4ty+3) ----
#pragma unroll
        for (int p = 0; p < 4; ++p) {
            const int ii = 4 * ty + p;
            const float aii = ai_r[p];
            const int   sii = si_r[p];
            float lg[4];
            float tmax = -INFINITY;
#pragma unroll
            for (int r = 0; r < 4; ++r) {
                const int jl = 4 * tx + r;
                float xv = CP[ii * 68 + jl] * isc;
                const float ajv = fabsf(sep[b * S_ + j0 + jl]);
                const int   sjv = seg[b * S_ + j0 + jl];
                const float gap = fabsf(aii - ajv);
                const float bias = (sii == sjv) ? sb
                                 : cb + __expf(-gap * dec) * ssc;
                xv += bias;
                if (mask[b * S_ + j0 + jl] == 0) xv = -9.0e15f;
                lg[r] = xv;
                tmax = fmaxf(tmax, xv);
            }
#pragma unroll
            for (int off = 1; off < 16; off <<= 1)
                tmax = fmaxf(tmax, __shfl_xor(tmax, off));
            const float mp = m_s[ii];
            const float nm = fmaxf(mp, tmax);
            const float alpha = __expf(mp - nm);
            float rs = 0.f;
            ushort4 pw;
#pragma unroll
            for (int r = 0; r < 4; ++r) {
                const float e = __expf(lg[r] - nm);
                rs += e;
                ((unsigned short*)&pw)[r] = f2bf(e);
            }
#pragma unroll
            for (int off = 1; off < 16; off <<= 1)
                rs += __shfl_xor(rs, off);
            if (tx == 0) {
                m_s[ii] = nm;
                alpha_s[ii] = alpha;
                l_s[ii] = l_s[ii] * alpha + rs;
            }
            *(ushort4*)&Pp[ii * 72 + 4 * tx] = pw;
        }

        // ---- PV (rows strip w): O += P x Vt ----
        float av[4];
#pragma unroll
        for (int reg = 0; reg < 4; ++reg)
            av[reg] = alpha_s[16 * w + quad * 4 + reg];
        bf16x8 pA[2];
#pragma unroll
        for (int ks = 0; ks < 2; ++ks)
            pA[ks] = __builtin_bit_cast(bf16x8,
                *(const ux4*)&Pp[(16 * w + l16) * 72 + ks * 32 + quad * 8]);
#pragma unroll
        for (int nd = 0; nd < 4; ++nd) {
#pragma unroll
            for (int reg = 0; reg < 4; ++reg) O[nd][reg] *= av[reg];
#pragma unroll
            for (int ks = 0; ks < 2; ++ks) {
                bf16x8 bf = gld8(vtbase + (size_t)(16 * nd + l16) * S_ + j0 + ks * 32 + quad * 8);
                O[nd] = __builtin_amdgcn_mfma_f32_16x16x32_bf16(pA[ks], bf, O[nd], 0, 0, 0);
            }
        }
    }

    // ---- epilogue: write UNNORMALIZED partial O + (m,l) ----
    const int idx = ((b * H_ + h) * 6 + it);          // 0..575
    unsigned short* pO = part_O + ((size_t)(jc * 576 + idx)) * 4096;
    float* pml = part_ml + (size_t)(jc * 576 + idx) * 128;
#pragma unroll
    for (int nd = 0; nd < 4; ++nd) {
        const int d = 16 * nd + l16;
#pragma unroll
        for (int reg = 0; reg < 4; ++reg) {
            const int ii = 16 * w + quad * 4 + reg;
            pO[ii * 64 + d] = f2bf(O[nd][reg]);
        }
    }
    if (lane < 16) {
        const int ii = 16 * w + lane;
        pml[ii]      = m_s[ii];
        pml[64 + ii] = l_s[ii];
    }
}

// ---------------------------------------------------------------------------
// Merge the 3 split-j partials -> vals (bf16, (B,S,E)). grid=576, 256 thr.
// ---------------------------------------------------------------------------
__global__ __launch_bounds__(256) void merge_attn(
    const unsigned short* __restrict__ part_O, const float* __restrict__ part_ml,
    unsigned short* __restrict__ vals)
{
    const int idx = blockIdx.x;                 // ((b*H+h)*6+it)
    const int b  = idx / (H_ * 6);
    const int r  = idx - b * H_ * 6;
    const int h  = r / 6, it = r - h * 6;
    const int tid = threadIdx.x;
    const int ii = tid >> 2, c = (tid & 3) * 16;

    float m[3], l[3];
#pragma unroll
    for (int jc = 0; jc < 3; ++jc) {
        const float* pml = part_ml + (size_t)(jc * 576 + idx) * 128;
        m[jc] = pml[ii];
        l[jc] = pml[64 + ii];
    }
    float M = fmaxf(fmaxf(m[0], m[1]), m[2]);
    float wsum = 0.f, wc[3];
#pragma unroll
    for (int jc = 0; jc < 3; ++jc) {
        wc[jc] = __expf(m[jc] - M);
        wsum += wc[jc] * l[jc];
    }
    const float inv = (wsum > 0.f) ? 1.f / wsum : 0.f;

    float o[16];
#pragma unroll
    for (int e = 0; e < 16; ++e) o[e] = 0.f;
#pragma unroll
    for (int jc = 0; jc < 3; ++jc) {
        const unsigned short* pO = part_O + ((size_t)(jc * 576 + idx)) * 4096
                                 + ii * 64 + c;
        ux4 u0 = *(const ux4*)pO;
        ux4 u1 = *(const ux4*)(pO + 8);
        const unsigned short* us0 = (const unsigned short*)&u0;
        const unsigned short* us1 = (const unsigned short*)&u1;
#pragma unroll
        for (int e = 0; e < 8; ++e) {
            o[e]     += wc[jc] * bf2f(us0[e]);
            o[8 + e] += wc[jc] * bf2f(us1[e]);
        }
    }
    ushort4 w0, w1, w2, w3;
#pragma unroll
    for (int e = 0; e < 4; ++e) {
        ((unsigned short*)&w0)[e] = f2bf(o[e] * inv);
        ((unsigned short*)&w1)[e] = f2bf(o[4 + e] * inv);
        ((unsigned short*)&w2)[e] = f2bf(o[8 + e] * inv);
        ((unsigned short*)&w3)[e] = f2bf(o[12 + e] * inv);
    }
    unsigned short* dst = vals + ((size_t)(b * S_ + it * 64 + ii)) * E_ + h * 64 + c;
    *(ushort4*)(dst)      = w0;
    *(ushort4*)(dst + 4)  = w1;
    *(ushort4*)(dst + 8)  = w2;
    *(ushort4*)(dst + 12) = w3;
}

// ---------------------------------------------------------------------------
// Launcher. Workspace: xb 2359296; 7x589824 weights/rel; qb,kb,vtb 3x2359296;
// pkb,pqb 2x589824; valsb 2359296; part_O 3x576x4096; part_ml fp32 3x576x128.
// ---------------------------------------------------------------------------
extern "C" void kernel_launch(void* const* d_in, const int* in_sizes, int n_in,
                              void* d_out, int out_size, void* d_ws, size_t ws_size,
                              hipStream_t stream)
{
    const float* x         = (const float*)d_in[0];
    const int*   mask      = (const int*)d_in[1];
    const int*   seg       = (const int*)d_in[2];
    const float* sep       = (const float*)d_in[3];
    const float* Wq        = (const float*)d_in[4];
    const float* bq        = (const float*)d_in[5];
    const float* Wk        = (const float*)d_in[6];
    const float* bk        = (const float*)d_in[7];
    const float* Wv        = (const float*)d_in[8];
    const float* bv        = (const float*)d_in[9];
    const float* rel_emb   = (const float*)d_in[10];
    const float* Wpk       = (const float*)d_in[11];
    const float* bpk       = (const float*)d_in[12];
    const float* Wpq       = (const float*)d_in[13];
    const float* bpq       = (const float*)d_in[14];
    const float* same_bias = (const float*)d_in[15];
    const float* cross_bias= (const float*)d_in[16];
    const float* sep_scale = (const float*)d_in[17];
    const float* sep_decay = (const float*)d_in[18];
    const float* Wo        = (const float*)d_in[19];
    const float* bo        = (const float*)d_in[20];

    const size_t QKVN = (size_t)B_ * S_ * E_;   // 2359296
    const size_t WN   = (size_t)768 * 768;      //  589824

    unsigned short* xb    = (unsigned short*)d_ws;
    unsigned short* wqb   = xb   + QKVN;
    unsigned short* wkb   = wqb  + WN;
    unsigned short* wvb   = wkb  + WN;
    unsigned short* wob   = wvb  + WN;
    unsigned short* wpkb  = wob  + WN;
    unsigned short* wpqb  = wpkb + WN;
    unsigned short* relb  = wpqb + WN;
    unsigned short* qb    = relb + WN;
    unsigned short* kb    = qb   + QKVN;
    unsigned short* vtb   = kb   + QKVN;
    unsigned short* pkb   = vtb  + QKVN;
    unsigned short* pqb   = pkb  + WN;
    unsigned short* valsb = pqb  + WN;
    unsigned short* partO = valsb + QKVN;                       // 3*576*4096 shorts
    float*          partml= (float*)(partO + (size_t)3 * 576 * 4096);

    // 1) convert all operands to bf16
    convert_all<<<dim3(576, 11), 256, 0, stream>>>(
        x, Wq, Wk, Wv, Wo, Wpk, Wpq, rel_emb + (size_t)128 * D_,
        xb, wqb, wkb, wvb, wob, wpkb, wpqb, relb);

    // 2) fused Q/K/Vt/pk/pq projections
    proj_all<<<dim3(6, 24, 5), 256, 0, stream>>>(
        xb, relb, wqb, wkb, wvb, wpkb, wpqb,
        bq, bk, bv, bpk, bpq, qb, kb, vtb, pkb, pqb);

    // 3) MFMA flash attention, barrier-free, split-j x3
    attn_mfma<<<dim3(6, 12, 24), 256, 0, stream>>>(
        qb, kb, vtb, pkb, pqb, seg, sep, mask,
        same_bias, cross_bias, sep_scale, sep_decay, partO, partml);

    // 4) merge partials -> valsb
    merge_attn<<<dim3(576), 256, 0, stream>>>(partO, partml, valsb);

    // 5) output projection
    gemm_out<<<dim3(6, 24), 256, 0, stream>>>(valsb, wob, bo, (float*)d_out);
}